// Round 1
// baseline (1337.397 us; speedup 1.0000x reference)
//
#include <hip/hip_runtime.h>
#include <hip/hip_bf16.h>
#include <math.h>

#define U_CNT 50000
#define I_CNT 50000
#define N_CNT 100000
#define D 64
#define NNZ_CNT 3200000
#define LAYERS 3
#define BATCH 4096
#define L2_REG_F 1e-5f
#define EPS_F 1e-12f

#define SCAN_NBLK 391  // ceil(100000/256)

// ---------------- init: E = concat(user_embed, item_embed); all_e[:,0:64] = E
__global__ void init_E(const float* __restrict__ ue, const float* __restrict__ ie,
                       float* __restrict__ E, float* __restrict__ all_e) {
    int tid = blockIdx.x * blockDim.x + threadIdx.x;
    if (tid >= N_CNT * D) return;
    int row = tid >> 6;
    int d = tid & 63;
    float v = (row < U_CNT) ? ue[tid] : ie[tid - U_CNT * D];
    E[tid] = v;
    all_e[(size_t)row * 256 + d] = v;
}

// ---------------- CSR build: histogram
__global__ void hist_rows(const int* __restrict__ rows, int* __restrict__ counts) {
    int e = blockIdx.x * blockDim.x + threadIdx.x;
    if (e < NNZ_CNT) atomicAdd(&counts[rows[e]], 1);
}

// block sums of counts (chunk=256)
__global__ void scan_phase1(const int* __restrict__ counts, int* __restrict__ blk_sums) {
    __shared__ int s[256];
    int t = threadIdx.x;
    int i = blockIdx.x * 256 + t;
    int v = (i < N_CNT) ? counts[i] : 0;
    s[t] = v;
    __syncthreads();
    for (int off = 128; off >= 1; off >>= 1) {
        if (t < off) s[t] += s[t + off];
        __syncthreads();
    }
    if (t == 0) blk_sums[blockIdx.x] = s[0];
}

// exclusive scan of block sums (NBLK <= 512), also writes row_ptr[N] = NNZ
__global__ void scan_phase2(int* __restrict__ blk_sums, int* __restrict__ row_ptr) {
    __shared__ int s[512];
    int t = threadIdx.x;
    int v = (t < SCAN_NBLK) ? blk_sums[t] : 0;
    s[t] = v;
    __syncthreads();
    for (int off = 1; off < 512; off <<= 1) {
        int x = (t >= off) ? s[t - off] : 0;
        __syncthreads();
        s[t] += x;
        __syncthreads();
    }
    if (t < SCAN_NBLK) blk_sums[t] = s[t] - v;  // exclusive
    if (t == 0) row_ptr[N_CNT] = NNZ_CNT;
}

// per-chunk exclusive scan + block offset -> row_ptr and offset (scatter cursor)
__global__ void scan_phase3(const int* __restrict__ counts, const int* __restrict__ blk_sums,
                            int* __restrict__ row_ptr, int* __restrict__ offset) {
    __shared__ int s[256];
    int t = threadIdx.x;
    int i = blockIdx.x * 256 + t;
    int v = (i < N_CNT) ? counts[i] : 0;
    s[t] = v;
    __syncthreads();
    for (int off = 1; off < 256; off <<= 1) {
        int x = (t >= off) ? s[t - off] : 0;
        __syncthreads();
        s[t] += x;
        __syncthreads();
    }
    int excl = s[t] - v + blk_sums[blockIdx.x];
    if (i < N_CNT) {
        row_ptr[i] = excl;
        offset[i] = excl;
    }
}

// scatter edges into CSR order as (val, col) pairs
__global__ void scatter_edges(const int* __restrict__ rows, const int* __restrict__ cols,
                              const float* __restrict__ vals, int* __restrict__ offset,
                              float2* __restrict__ packed) {
    int e = blockIdx.x * blockDim.x + threadIdx.x;
    if (e >= NNZ_CNT) return;
    int r = rows[e];
    int p = atomicAdd(&offset[r], 1);
    packed[p] = make_float2(vals[e], __int_as_float(cols[e]));
}

// ---------------- SpMM: one wave per row, lane = dim
__global__ __launch_bounds__(256) void spmm(const float2* __restrict__ packed,
                                            const int* __restrict__ row_ptr,
                                            const float* __restrict__ E,
                                            float* __restrict__ Lm) {
    int wid = (blockIdx.x * blockDim.x + threadIdx.x) >> 6;
    int lane = threadIdx.x & 63;
    if (wid >= N_CNT) return;
    int s = row_ptr[wid];
    int e = row_ptr[wid + 1];
    float acc = 0.f;
    int i = s;
    if ((i & 1) && i < e) {  // align to even index for float4 pair loads
        float2 pv = packed[i];
        acc += pv.x * E[(size_t)__float_as_int(pv.y) * D + lane];
        i++;
    }
    for (; i + 2 <= e; i += 2) {
        float4 pv = *(const float4*)&packed[i];
        int c0 = __float_as_int(pv.y);
        int c1 = __float_as_int(pv.w);
        float e0 = E[(size_t)c0 * D + lane];
        float e1 = E[(size_t)c1 * D + lane];
        acc += pv.x * e0;
        acc += pv.z * e1;
    }
    if (i < e) {
        float2 pv = packed[i];
        acc += pv.x * E[(size_t)__float_as_int(pv.y) * D + lane];
    }
    Lm[wid * D + lane] = acc;
}

// ---------------- fused layer: x1 = Lm + E, x2 = Lm*E ; y = leaky(x1@W1 + x2@W2 + b1+b2)
// writes un-normalized y back to E, normalized y to all_e[:, (layer+1)*64 : ...]
#define TILE_ROWS 32  // 4 waves * 8 rows
__global__ __launch_bounds__(256) void layer_fused(const float* __restrict__ Lm, float* E,
                                                   const float* __restrict__ W1,
                                                   const float* __restrict__ b1,
                                                   const float* __restrict__ W2,
                                                   const float* __restrict__ b2,
                                                   float* __restrict__ all_e, int layer) {
    __shared__ float sW1[64 * 64];
    __shared__ float sW2[64 * 64];
    __shared__ float sB[64];
    __shared__ float sX[4][2][8][64];  // wave-private staging

    int t = threadIdx.x;
    for (int i = t; i < 4096; i += 256) {
        sW1[i] = W1[i];
        sW2[i] = W2[i];
    }
    if (t < 64) sB[t] = b1[t] + b2[t];
    __syncthreads();

    int w = t >> 6;
    int lane = t & 63;
    int col_off = (layer + 1) * 64;

    for (int tile = blockIdx.x; tile < N_CNT / TILE_ROWS; tile += gridDim.x) {
        int rowbase = tile * TILE_ROWS + w * 8;
#pragma unroll
        for (int r = 0; r < 8; r++) {
            int row = rowbase + r;
            float l = Lm[row * D + lane];
            float ev = E[row * D + lane];
            sX[w][0][r][lane] = l + ev;   // A_mul
            sX[w][1][r][lane] = l * ev;   // L_mul * E
        }
        float acc[8];
        float bb = sB[lane];
#pragma unroll
        for (int r = 0; r < 8; r++) acc[r] = bb;

        for (int k = 0; k < 64; k += 4) {
            float w1a = sW1[(k + 0) * 64 + lane];
            float w1b = sW1[(k + 1) * 64 + lane];
            float w1c = sW1[(k + 2) * 64 + lane];
            float w1d = sW1[(k + 3) * 64 + lane];
            float w2a = sW2[(k + 0) * 64 + lane];
            float w2b = sW2[(k + 1) * 64 + lane];
            float w2c = sW2[(k + 2) * 64 + lane];
            float w2d = sW2[(k + 3) * 64 + lane];
#pragma unroll
            for (int r = 0; r < 8; r++) {
                float4 x1 = *(const float4*)&sX[w][0][r][k];
                float4 x2 = *(const float4*)&sX[w][1][r][k];
                acc[r] += x1.x * w1a + x1.y * w1b + x1.z * w1c + x1.w * w1d +
                          x2.x * w2a + x2.y * w2b + x2.z * w2c + x2.w * w2d;
            }
        }
#pragma unroll
        for (int r = 0; r < 8; r++) {
            int row = rowbase + r;
            float y = acc[r];
            y = (y > 0.f) ? y : 0.2f * y;
            float ss = y * y;
#pragma unroll
            for (int off = 32; off >= 1; off >>= 1) ss += __shfl_xor(ss, off, 64);
            float nrm = fmaxf(sqrtf(ss), EPS_F);
            E[row * D + lane] = y;
            all_e[(size_t)row * 256 + col_off + lane] = y / nrm;
        }
    }
}

// ---------------- scoring: one wave per sample
__device__ __forceinline__ float dot4(float4 a, float4 b) {
    return a.x * b.x + a.y * b.y + a.z * b.z + a.w * b.w;
}

__global__ __launch_bounds__(256) void score_kernel(const float* __restrict__ all_e,
                                                    const int* __restrict__ users,
                                                    const int* __restrict__ pos,
                                                    const int* __restrict__ neg,
                                                    float* __restrict__ sums) {
    int wid = (blockIdx.x * blockDim.x + threadIdx.x) >> 6;
    int lane = threadIdx.x & 63;
    if (wid >= BATCH) return;
    int ui = users[wid];
    int pi = pos[wid];
    int ni = neg[wid];
    const float4* uv4 = (const float4*)(all_e + (size_t)ui * 256);
    const float4* pv4 = (const float4*)(all_e + (size_t)pi * 256);
    const float4* nv4 = (const float4*)(all_e + (size_t)ni * 256);
    float4 uv = uv4[lane];
    float4 pv = pv4[lane];
    float4 nv = nv4[lane];
    float s_up = dot4(uv, pv);
    float s_un = dot4(uv, nv);
    float s_uu = dot4(uv, uv);
    float s_pp = dot4(pv, pv);
    float s_nn = dot4(nv, nv);
#pragma unroll
    for (int off = 32; off >= 1; off >>= 1) {
        s_up += __shfl_xor(s_up, off, 64);
        s_un += __shfl_xor(s_un, off, 64);
        s_uu += __shfl_xor(s_uu, off, 64);
        s_pp += __shfl_xor(s_pp, off, 64);
        s_nn += __shfl_xor(s_nn, off, 64);
    }
    if (lane == 0) {
        float x = s_up - s_un;
        // log_sigmoid(x) = min(x,0) - log1p(exp(-|x|))
        float ls = fminf(x, 0.f) - log1pf(expf(-fabsf(x)));
        atomicAdd(&sums[0], -ls);
        atomicAdd(&sums[1], s_uu);
        atomicAdd(&sums[2], s_pp);
        atomicAdd(&sums[3], s_nn);
    }
}

__global__ void finalize(const float* __restrict__ sums, float* __restrict__ out) {
    float bpr = sums[0] / (float)BATCH;
    float l2norm = (sums[1] + sums[2] + sqrtf(sums[3])) * 0.5f;
    out[0] = bpr + L2_REG_F * l2norm / (float)BATCH;
}

extern "C" void kernel_launch(void* const* d_in, const int* in_sizes, int n_in,
                              void* d_out, int out_size, void* d_ws, size_t ws_size,
                              hipStream_t stream) {
    const int* users = (const int*)d_in[0];
    const int* pos_items = (const int*)d_in[1];
    const int* neg_items = (const int*)d_in[2];
    const int* rows = (const int*)d_in[3];
    const int* cols = (const int*)d_in[4];
    const float* vals = (const float*)d_in[5];
    const float* user_embed = (const float*)d_in[6];
    const float* item_embed = (const float*)d_in[7];
    const float* W1 = (const float*)d_in[8];
    const float* b1 = (const float*)d_in[9];
    const float* W2 = (const float*)d_in[10];
    const float* b2 = (const float*)d_in[11];
    float* out = (float*)d_out;

    char* ws = (char*)d_ws;
    // workspace layout (16B aligned)
    size_t off_alle = 0;                                   // N*256*4 = 102,400,000
    size_t off_E = off_alle + (size_t)N_CNT * 256 * 4;     // 25,600,000
    size_t off_Lm = off_E + (size_t)N_CNT * D * 4;         // 25,600,000
    size_t off_packed = off_Lm + (size_t)N_CNT * D * 4;    // 25,600,000
    size_t off_rowptr = off_packed + (size_t)NNZ_CNT * 8;  // 400,128
    size_t off_offset = off_rowptr + 400128;               // 400,128
    size_t off_counts = off_offset + 400128;               // 400,128
    size_t off_blks = off_counts + 400128;                 // 2048
    size_t off_sums = off_blks + 2048;                     // 16

    float* all_e = (float*)(ws + off_alle);
    float* E = (float*)(ws + off_E);
    float* Lm = (float*)(ws + off_Lm);
    float2* packed = (float2*)(ws + off_packed);
    int* row_ptr = (int*)(ws + off_rowptr);
    int* offset = (int*)(ws + off_offset);
    int* counts = (int*)(ws + off_counts);
    int* blk_sums = (int*)(ws + off_blks);
    float* sums = (float*)(ws + off_sums);

    hipMemsetAsync(counts, 0, (size_t)N_CNT * 4, stream);
    hipMemsetAsync(sums, 0, 16, stream);

    init_E<<<(N_CNT * D) / 256, 256, 0, stream>>>(user_embed, item_embed, E, all_e);

    // CSR build (done once; graph shared across layers)
    hist_rows<<<(NNZ_CNT + 255) / 256, 256, 0, stream>>>(rows, counts);
    scan_phase1<<<SCAN_NBLK, 256, 0, stream>>>(counts, blk_sums);
    scan_phase2<<<1, 512, 0, stream>>>(blk_sums, row_ptr);
    scan_phase3<<<SCAN_NBLK, 256, 0, stream>>>(counts, blk_sums, row_ptr, offset);
    scatter_edges<<<(NNZ_CNT + 255) / 256, 256, 0, stream>>>(rows, cols, vals, offset, packed);

    for (int l = 0; l < LAYERS; l++) {
        spmm<<<(N_CNT * 64) / 256, 256, 0, stream>>>(packed, row_ptr, E, Lm);
        layer_fused<<<1024, 256, 0, stream>>>(Lm, E, W1 + (size_t)l * 4096, b1 + (size_t)l * 64,
                                              W2 + (size_t)l * 4096, b2 + (size_t)l * 64,
                                              all_e, l);
    }

    score_kernel<<<(BATCH * 64) / 256, 256, 0, stream>>>(all_e, users, pos_items, neg_items, sums);
    finalize<<<1, 1, 0, stream>>>(sums, out);
}

// Round 2
// 1300.343 us; speedup vs baseline: 1.0285x; 1.0285x over previous
//
#include <hip/hip_runtime.h>
#include <hip/hip_bf16.h>
#include <math.h>

#define U_CNT 50000
#define I_CNT 50000
#define N_CNT 100000
#define D 64
#define NNZ_CNT 3200000
#define LAYERS 3
#define BATCH 4096
#define L2_REG_F 1e-5f
#define EPS_F 1e-12f

#define SCAN_NBLK 391   // ceil(100000/256)
#define NBUCKET 391     // 256 rows per bucket

__device__ __forceinline__ unsigned short f32_to_bf16(float f) {
    unsigned int u = __float_as_uint(f);
    u += 0x7FFFu + ((u >> 16) & 1u);   // round-to-nearest-even
    return (unsigned short)(u >> 16);
}
__device__ __forceinline__ float bf16_to_f32(unsigned short h) {
    return __uint_as_float(((unsigned int)h) << 16);
}

// ---------------- init: all_e[:,0:64] = concat(ue,ie) fp32; E_bf = bf16 copy
__global__ void init_E(const float* __restrict__ ue, const float* __restrict__ ie,
                       unsigned short* __restrict__ Ebf, float* __restrict__ all_e) {
    int tid = blockIdx.x * blockDim.x + threadIdx.x;
    if (tid >= N_CNT * D) return;
    int row = tid >> 6;
    int d = tid & 63;
    float v = (row < U_CNT) ? ue[tid] : ie[tid - U_CNT * D];
    Ebf[tid] = f32_to_bf16(v);
    all_e[(size_t)row * 256 + d] = v;
}

// ---------------- CSR build: histogram
__global__ void hist_rows(const int* __restrict__ rows, int* __restrict__ counts) {
    int e = blockIdx.x * blockDim.x + threadIdx.x;
    if (e < NNZ_CNT) atomicAdd(&counts[rows[e]], 1);
}

__global__ void scan_phase1(const int* __restrict__ counts, int* __restrict__ blk_sums) {
    __shared__ int s[256];
    int t = threadIdx.x;
    int i = blockIdx.x * 256 + t;
    int v = (i < N_CNT) ? counts[i] : 0;
    s[t] = v;
    __syncthreads();
    for (int off = 128; off >= 1; off >>= 1) {
        if (t < off) s[t] += s[t + off];
        __syncthreads();
    }
    if (t == 0) blk_sums[blockIdx.x] = s[0];
}

__global__ void scan_phase2(int* __restrict__ blk_sums, int* __restrict__ row_ptr) {
    __shared__ int s[512];
    int t = threadIdx.x;
    int v = (t < SCAN_NBLK) ? blk_sums[t] : 0;
    s[t] = v;
    __syncthreads();
    for (int off = 1; off < 512; off <<= 1) {
        int x = (t >= off) ? s[t - off] : 0;
        __syncthreads();
        s[t] += x;
        __syncthreads();
    }
    if (t < SCAN_NBLK) blk_sums[t] = s[t] - v;  // exclusive
    if (t == 0) row_ptr[N_CNT] = NNZ_CNT;
}

__global__ void scan_phase3(const int* __restrict__ counts, const int* __restrict__ blk_sums,
                            int* __restrict__ row_ptr) {
    __shared__ int s[256];
    int t = threadIdx.x;
    int i = blockIdx.x * 256 + t;
    int v = (i < N_CNT) ? counts[i] : 0;
    s[t] = v;
    __syncthreads();
    for (int off = 1; off < 256; off <<= 1) {
        int x = (t >= off) ? s[t - off] : 0;
        __syncthreads();
        s[t] += x;
        __syncthreads();
    }
    if (i < N_CNT) row_ptr[i] = s[t] - v + blk_sums[blockIdx.x];
}

// bucket cursor init: bcur[b] = row_ptr[b*256], one cursor per 64B line
__global__ void binit(const int* __restrict__ row_ptr, int* __restrict__ bcur) {
    int b = blockIdx.x * 256 + threadIdx.x;
    if (b < NBUCKET) bcur[b * 16] = row_ptr[b << 8];
}

// phase 1: append edge to its row-bucket (writes land in 391 hot regions -> L2-merged)
__global__ void bucket_append(const int* __restrict__ rows, const int* __restrict__ cols,
                              const float* __restrict__ vals, int* __restrict__ bcur,
                              float2* __restrict__ bbuf) {
    int e = blockIdx.x * blockDim.x + threadIdx.x;
    if (e >= NNZ_CNT) return;
    int r = rows[e];
    int b = r >> 8;
    int p = atomicAdd(&bcur[b * 16], 1);
    unsigned int bits = ((unsigned int)(r & 255) << 17) | (unsigned int)cols[e];
    bbuf[p] = make_float2(vals[e], __uint_as_float(bits));
}

// phase 2: per-bucket CSR finalize with LDS row cursors; writes hit a ~65KB L2-hot window
__global__ __launch_bounds__(256) void csr_finalize(const float2* __restrict__ bbuf,
                                                    const int* __restrict__ row_ptr,
                                                    float2* __restrict__ packed) {
    __shared__ int cur[256];
    int base = blockIdx.x << 8;
    int hi = min(base + 256, N_CNT);
    int t = threadIdx.x;
    if (base + t < hi) cur[t] = row_ptr[base + t];
    __syncthreads();
    int s = row_ptr[base];
    int e = row_ptr[hi];
    for (int i = s + t; i < e; i += 256) {
        float2 rec = bbuf[i];
        unsigned int bits = __float_as_uint(rec.y);
        int rl = bits >> 17;
        int c = (int)(bits & 0x1FFFFu);
        int p = atomicAdd(&cur[rl], 1);
        packed[p] = make_float2(rec.x, __int_as_float(c));
    }
}

// ---------------- SpMM: one wave per row; 2 edges/iter (half-wave each), bf16 E gathers
__global__ __launch_bounds__(256) void spmm_bf16(const float2* __restrict__ packed,
                                                 const int* __restrict__ row_ptr,
                                                 const unsigned short* __restrict__ Ebf,
                                                 float* __restrict__ Lm) {
    int wid = (blockIdx.x * blockDim.x + threadIdx.x) >> 6;
    int lane = threadIdx.x & 63;
    if (wid >= N_CNT) return;
    int s = row_ptr[wid];
    int e = row_ptr[wid + 1];
    int half = lane >> 5;   // which edge of the pair
    int hl = lane & 31;     // dim pair: handles dims 2*hl, 2*hl+1
    float acc0 = 0.f, acc1 = 0.f;
    for (int i = s + half; i < e; i += 2) {
        float2 rec = packed[i];
        int c = __float_as_int(rec.y);
        unsigned int ev = *(const unsigned int*)(Ebf + (size_t)c * D + 2 * hl);
        float e0 = __uint_as_float((ev & 0xFFFFu) << 16);
        float e1 = __uint_as_float(ev & 0xFFFF0000u);
        acc0 += rec.x * e0;
        acc1 += rec.x * e1;
    }
    acc0 += __shfl_xor(acc0, 32, 64);
    acc1 += __shfl_xor(acc1, 32, 64);
    if (half == 0) {
        *(float2*)(Lm + (size_t)wid * D + 2 * hl) = make_float2(acc0, acc1);
    }
}

// ---------------- fused layer: x1 = Lm + E, x2 = Lm*E ; y = leaky(x1@W1 + x2@W2 + b1+b2)
// un-normalized y -> E_bf (bf16), normalized y -> all_e[:, (layer+1)*64:...]
#define TILE_ROWS 32  // 4 waves * 8 rows
__global__ __launch_bounds__(256) void layer_fused(const float* __restrict__ Lm,
                                                   unsigned short* __restrict__ Ebf,
                                                   const float* __restrict__ W1,
                                                   const float* __restrict__ b1,
                                                   const float* __restrict__ W2,
                                                   const float* __restrict__ b2,
                                                   float* __restrict__ all_e, int layer) {
    __shared__ float sW1[64 * 64];
    __shared__ float sW2[64 * 64];
    __shared__ float sB[64];
    __shared__ float sX[4][2][8][64];  // wave-private staging

    int t = threadIdx.x;
    for (int i = t; i < 4096; i += 256) {
        sW1[i] = W1[i];
        sW2[i] = W2[i];
    }
    if (t < 64) sB[t] = b1[t] + b2[t];
    __syncthreads();

    int w = t >> 6;
    int lane = t & 63;
    int col_off = (layer + 1) * 64;

    for (int tile = blockIdx.x; tile < N_CNT / TILE_ROWS; tile += gridDim.x) {
        int rowbase = tile * TILE_ROWS + w * 8;
#pragma unroll
        for (int r = 0; r < 8; r++) {
            int row = rowbase + r;
            float l = Lm[row * D + lane];
            float ev = bf16_to_f32(Ebf[row * D + lane]);
            sX[w][0][r][lane] = l + ev;   // A_mul
            sX[w][1][r][lane] = l * ev;   // L_mul * E
        }
        float acc[8];
        float bb = sB[lane];
#pragma unroll
        for (int r = 0; r < 8; r++) acc[r] = bb;

        for (int k = 0; k < 64; k += 4) {
            float w1a = sW1[(k + 0) * 64 + lane];
            float w1b = sW1[(k + 1) * 64 + lane];
            float w1c = sW1[(k + 2) * 64 + lane];
            float w1d = sW1[(k + 3) * 64 + lane];
            float w2a = sW2[(k + 0) * 64 + lane];
            float w2b = sW2[(k + 1) * 64 + lane];
            float w2c = sW2[(k + 2) * 64 + lane];
            float w2d = sW2[(k + 3) * 64 + lane];
#pragma unroll
            for (int r = 0; r < 8; r++) {
                float4 x1 = *(const float4*)&sX[w][0][r][k];
                float4 x2 = *(const float4*)&sX[w][1][r][k];
                acc[r] += x1.x * w1a + x1.y * w1b + x1.z * w1c + x1.w * w1d +
                          x2.x * w2a + x2.y * w2b + x2.z * w2c + x2.w * w2d;
            }
        }
#pragma unroll
        for (int r = 0; r < 8; r++) {
            int row = rowbase + r;
            float y = acc[r];
            y = (y > 0.f) ? y : 0.2f * y;
            float ss = y * y;
#pragma unroll
            for (int off = 32; off >= 1; off >>= 1) ss += __shfl_xor(ss, off, 64);
            float nrm = fmaxf(sqrtf(ss), EPS_F);
            Ebf[row * D + lane] = f32_to_bf16(y);
            all_e[(size_t)row * 256 + col_off + lane] = y / nrm;
        }
    }
}

// ---------------- scoring: one wave per sample
__device__ __forceinline__ float dot4(float4 a, float4 b) {
    return a.x * b.x + a.y * b.y + a.z * b.z + a.w * b.w;
}

__global__ __launch_bounds__(256) void score_kernel(const float* __restrict__ all_e,
                                                    const int* __restrict__ users,
                                                    const int* __restrict__ pos,
                                                    const int* __restrict__ neg,
                                                    float* __restrict__ sums) {
    int wid = (blockIdx.x * blockDim.x + threadIdx.x) >> 6;
    int lane = threadIdx.x & 63;
    if (wid >= BATCH) return;
    int ui = users[wid];
    int pi = pos[wid];
    int ni = neg[wid];
    const float4* uv4 = (const float4*)(all_e + (size_t)ui * 256);
    const float4* pv4 = (const float4*)(all_e + (size_t)pi * 256);
    const float4* nv4 = (const float4*)(all_e + (size_t)ni * 256);
    float4 uv = uv4[lane];
    float4 pv = pv4[lane];
    float4 nv = nv4[lane];
    float s_up = dot4(uv, pv);
    float s_un = dot4(uv, nv);
    float s_uu = dot4(uv, uv);
    float s_pp = dot4(pv, pv);
    float s_nn = dot4(nv, nv);
#pragma unroll
    for (int off = 32; off >= 1; off >>= 1) {
        s_up += __shfl_xor(s_up, off, 64);
        s_un += __shfl_xor(s_un, off, 64);
        s_uu += __shfl_xor(s_uu, off, 64);
        s_pp += __shfl_xor(s_pp, off, 64);
        s_nn += __shfl_xor(s_nn, off, 64);
    }
    if (lane == 0) {
        float x = s_up - s_un;
        float ls = fminf(x, 0.f) - log1pf(expf(-fabsf(x)));  // log_sigmoid
        atomicAdd(&sums[0], -ls);
        atomicAdd(&sums[1], s_uu);
        atomicAdd(&sums[2], s_pp);
        atomicAdd(&sums[3], s_nn);
    }
}

__global__ void finalize(const float* __restrict__ sums, float* __restrict__ out) {
    float bpr = sums[0] / (float)BATCH;
    float l2norm = (sums[1] + sums[2] + sqrtf(sums[3])) * 0.5f;
    out[0] = bpr + L2_REG_F * l2norm / (float)BATCH;
}

extern "C" void kernel_launch(void* const* d_in, const int* in_sizes, int n_in,
                              void* d_out, int out_size, void* d_ws, size_t ws_size,
                              hipStream_t stream) {
    const int* users = (const int*)d_in[0];
    const int* pos_items = (const int*)d_in[1];
    const int* neg_items = (const int*)d_in[2];
    const int* rows = (const int*)d_in[3];
    const int* cols = (const int*)d_in[4];
    const float* vals = (const float*)d_in[5];
    const float* user_embed = (const float*)d_in[6];
    const float* item_embed = (const float*)d_in[7];
    const float* W1 = (const float*)d_in[8];
    const float* b1 = (const float*)d_in[9];
    const float* W2 = (const float*)d_in[10];
    const float* b2 = (const float*)d_in[11];
    float* out = (float*)d_out;

    char* ws = (char*)d_ws;
    // workspace layout (128B-aligned chunks), total ~167 MB
    size_t off_alle = 0;                                     // 102,400,000
    size_t off_Lm = off_alle + (size_t)N_CNT * 256 * 4;      // 25,600,000
    size_t off_packed = off_Lm + (size_t)N_CNT * D * 4;      // 25,600,000
    size_t off_Ebf = off_packed + (size_t)NNZ_CNT * 8;       // 12,800,000
    size_t off_rowptr = off_Ebf + (size_t)N_CNT * D * 2;     // 400,128
    size_t off_counts = off_rowptr + 400128;                 // 400,128
    size_t off_blks = off_counts + 400128;                   // 2,048
    size_t off_bcur = off_blks + 2048;                       // 25,088 (391 cursors, 64B apart)
    size_t off_sums = off_bcur + 25088;                      // 16

    float* all_e = (float*)(ws + off_alle);
    float2* bbuf = (float2*)(ws + off_alle);   // aliases all_e; dead before init_E runs
    float* Lm = (float*)(ws + off_Lm);
    float2* packed = (float2*)(ws + off_packed);
    unsigned short* Ebf = (unsigned short*)(ws + off_Ebf);
    int* row_ptr = (int*)(ws + off_rowptr);
    int* counts = (int*)(ws + off_counts);
    int* blk_sums = (int*)(ws + off_blks);
    int* bcur = (int*)(ws + off_bcur);
    float* sums = (float*)(ws + off_sums);

    hipMemsetAsync(counts, 0, (size_t)N_CNT * 4, stream);
    hipMemsetAsync(sums, 0, 16, stream);

    // CSR build (bucketed two-phase scatter)
    hist_rows<<<(NNZ_CNT + 255) / 256, 256, 0, stream>>>(rows, counts);
    scan_phase1<<<SCAN_NBLK, 256, 0, stream>>>(counts, blk_sums);
    scan_phase2<<<1, 512, 0, stream>>>(blk_sums, row_ptr);
    scan_phase3<<<SCAN_NBLK, 256, 0, stream>>>(counts, blk_sums, row_ptr);
    binit<<<2, 256, 0, stream>>>(row_ptr, bcur);
    bucket_append<<<(NNZ_CNT + 255) / 256, 256, 0, stream>>>(rows, cols, vals, bcur, bbuf);
    csr_finalize<<<NBUCKET, 256, 0, stream>>>(bbuf, row_ptr, packed);

    // embeddings (after csr_finalize: bbuf aliases all_e)
    init_E<<<(N_CNT * D) / 256, 256, 0, stream>>>(user_embed, item_embed, Ebf, all_e);

    for (int l = 0; l < LAYERS; l++) {
        spmm_bf16<<<(N_CNT * 64) / 256, 256, 0, stream>>>(packed, row_ptr, Ebf, Lm);
        layer_fused<<<1024, 256, 0, stream>>>(Lm, Ebf, W1 + (size_t)l * 4096, b1 + (size_t)l * 64,
                                              W2 + (size_t)l * 4096, b2 + (size_t)l * 64,
                                              all_e, l);
    }

    score_kernel<<<(BATCH * 64) / 256, 256, 0, stream>>>(all_e, users, pos_items, neg_items, sums);
    finalize<<<1, 1, 0, stream>>>(sums, out);
}

// Round 3
// 1093.124 us; speedup vs baseline: 1.2235x; 1.1896x over previous
//
#include <hip/hip_runtime.h>
#include <hip/hip_bf16.h>
#include <math.h>

#define U_CNT 50000
#define I_CNT 50000
#define N_CNT 100000
#define D 64
#define NNZ_CNT 3200000
#define LAYERS 3
#define BATCH 4096
#define L2_REG_F 1e-5f
#define EPS_F 1e-12f

#define SCAN_NBLK 391   // ceil(100000/256)
#define NBUCKET 391     // 256 rows per bucket

__device__ __forceinline__ unsigned short f32_to_bf16(float f) {
    unsigned int u = __float_as_uint(f);
    u += 0x7FFFu + ((u >> 16) & 1u);   // round-to-nearest-even
    return (unsigned short)(u >> 16);
}
__device__ __forceinline__ float bf16_to_f32(unsigned short h) {
    return __uint_as_float(((unsigned int)h) << 16);
}

// ---------------- init: all_e[:,0:64] = concat(ue,ie) fp32; E_bf = bf16 copy
__global__ void init_E(const float* __restrict__ ue, const float* __restrict__ ie,
                       unsigned short* __restrict__ Ebf, float* __restrict__ all_e) {
    int tid = blockIdx.x * blockDim.x + threadIdx.x;
    if (tid >= N_CNT * D) return;
    int row = tid >> 6;
    int d = tid & 63;
    float v = (row < U_CNT) ? ue[tid] : ie[tid - U_CNT * D];
    Ebf[tid] = f32_to_bf16(v);
    all_e[(size_t)row * 256 + d] = v;
}

// ---------------- CSR build: histogram
__global__ void hist_rows(const int* __restrict__ rows, int* __restrict__ counts) {
    int e = blockIdx.x * blockDim.x + threadIdx.x;
    if (e < NNZ_CNT) atomicAdd(&counts[rows[e]], 1);
}

__global__ void scan_phase1(const int* __restrict__ counts, int* __restrict__ blk_sums) {
    __shared__ int s[256];
    int t = threadIdx.x;
    int i = blockIdx.x * 256 + t;
    int v = (i < N_CNT) ? counts[i] : 0;
    s[t] = v;
    __syncthreads();
    for (int off = 128; off >= 1; off >>= 1) {
        if (t < off) s[t] += s[t + off];
        __syncthreads();
    }
    if (t == 0) blk_sums[blockIdx.x] = s[0];
}

__global__ void scan_phase2(int* __restrict__ blk_sums, int* __restrict__ row_ptr) {
    __shared__ int s[512];
    int t = threadIdx.x;
    int v = (t < SCAN_NBLK) ? blk_sums[t] : 0;
    s[t] = v;
    __syncthreads();
    for (int off = 1; off < 512; off <<= 1) {
        int x = (t >= off) ? s[t - off] : 0;
        __syncthreads();
        s[t] += x;
        __syncthreads();
    }
    if (t < SCAN_NBLK) blk_sums[t] = s[t] - v;  // exclusive
    if (t == 0) row_ptr[N_CNT] = NNZ_CNT;
}

__global__ void scan_phase3(const int* __restrict__ counts, const int* __restrict__ blk_sums,
                            int* __restrict__ row_ptr) {
    __shared__ int s[256];
    int t = threadIdx.x;
    int i = blockIdx.x * 256 + t;
    int v = (i < N_CNT) ? counts[i] : 0;
    s[t] = v;
    __syncthreads();
    for (int off = 1; off < 256; off <<= 1) {
        int x = (t >= off) ? s[t - off] : 0;
        __syncthreads();
        s[t] += x;
        __syncthreads();
    }
    if (i < N_CNT) row_ptr[i] = s[t] - v + blk_sums[blockIdx.x];
}

// bucket cursor init: bcur[b] = row_ptr[b*256], one cursor per 64B line
__global__ void binit(const int* __restrict__ row_ptr, int* __restrict__ bcur) {
    int b = blockIdx.x * 256 + threadIdx.x;
    if (b < NBUCKET) bcur[b * 16] = row_ptr[b << 8];
}

// phase 1: append edge to its row-bucket (writes land in 391 hot regions -> L2-merged)
__global__ void bucket_append(const int* __restrict__ rows, const int* __restrict__ cols,
                              const float* __restrict__ vals, int* __restrict__ bcur,
                              float2* __restrict__ bbuf) {
    int e = blockIdx.x * blockDim.x + threadIdx.x;
    if (e >= NNZ_CNT) return;
    int r = rows[e];
    int b = r >> 8;
    int p = atomicAdd(&bcur[b * 16], 1);
    unsigned int bits = ((unsigned int)(r & 255) << 17) | (unsigned int)cols[e];
    bbuf[p] = make_float2(vals[e], __uint_as_float(bits));
}

// phase 2: per-bucket CSR finalize with LDS row cursors; writes hit a ~65KB L2-hot window
__global__ __launch_bounds__(256) void csr_finalize(const float2* __restrict__ bbuf,
                                                    const int* __restrict__ row_ptr,
                                                    float2* __restrict__ packed) {
    __shared__ int cur[256];
    int base = blockIdx.x << 8;
    int hi = min(base + 256, N_CNT);
    int t = threadIdx.x;
    if (base + t < hi) cur[t] = row_ptr[base + t];
    __syncthreads();
    int s = row_ptr[base];
    int e = row_ptr[hi];
    for (int i = s + t; i < e; i += 256) {
        float2 rec = bbuf[i];
        unsigned int bits = __float_as_uint(rec.y);
        int rl = bits >> 17;
        int c = (int)(bits & 0x1FFFFu);
        int p = atomicAdd(&cur[rl], 1);
        packed[p] = make_float2(rec.x, __int_as_float(c));
    }
}

// ---------------- SpMM: one wave per row; 2 edges/iter (half-wave each), bf16 E gathers
__global__ __launch_bounds__(256) void spmm_bf16(const float2* __restrict__ packed,
                                                 const int* __restrict__ row_ptr,
                                                 const unsigned short* __restrict__ Ebf,
                                                 float* __restrict__ Lm) {
    int wid = (blockIdx.x * blockDim.x + threadIdx.x) >> 6;
    int lane = threadIdx.x & 63;
    if (wid >= N_CNT) return;
    int s = row_ptr[wid];
    int e = row_ptr[wid + 1];
    int half = lane >> 5;   // which edge of the pair
    int hl = lane & 31;     // dim pair: handles dims 2*hl, 2*hl+1
    float acc0 = 0.f, acc1 = 0.f;
    for (int i = s + half; i < e; i += 2) {
        float2 rec = packed[i];
        int c = __float_as_int(rec.y);
        unsigned int ev = *(const unsigned int*)(Ebf + (size_t)c * D + 2 * hl);
        float e0 = __uint_as_float((ev & 0xFFFFu) << 16);
        float e1 = __uint_as_float(ev & 0xFFFF0000u);
        acc0 += rec.x * e0;
        acc1 += rec.x * e1;
    }
    acc0 += __shfl_xor(acc0, 32, 64);
    acc1 += __shfl_xor(acc1, 32, 64);
    if (half == 0) {
        *(float2*)(Lm + (size_t)wid * D + 2 * hl) = make_float2(acc0, acc1);
    }
}

// ---------------- fused layer: x1 = Lm + E, x2 = Lm*E ; y = leaky(x1@W1 + x2@W2 + b1+b2)
// un-normalized y -> E_bf (bf16), normalized y -> all_e[:, (layer+1)*64:...]
#define TILE_ROWS 32  // 4 waves * 8 rows
__global__ __launch_bounds__(256) void layer_fused(const float* __restrict__ Lm,
                                                   unsigned short* __restrict__ Ebf,
                                                   const float* __restrict__ W1,
                                                   const float* __restrict__ b1,
                                                   const float* __restrict__ W2,
                                                   const float* __restrict__ b2,
                                                   float* __restrict__ all_e, int layer) {
    __shared__ float sW1[64 * 64];
    __shared__ float sW2[64 * 64];
    __shared__ float sB[64];
    __shared__ float sX[4][2][8][64];  // wave-private staging

    int t = threadIdx.x;
    for (int i = t; i < 4096; i += 256) {
        sW1[i] = W1[i];
        sW2[i] = W2[i];
    }
    if (t < 64) sB[t] = b1[t] + b2[t];
    __syncthreads();

    int w = t >> 6;
    int lane = t & 63;
    int col_off = (layer + 1) * 64;

    for (int tile = blockIdx.x; tile < N_CNT / TILE_ROWS; tile += gridDim.x) {
        int rowbase = tile * TILE_ROWS + w * 8;
#pragma unroll
        for (int r = 0; r < 8; r++) {
            int row = rowbase + r;
            float l = Lm[row * D + lane];
            float ev = bf16_to_f32(Ebf[row * D + lane]);
            sX[w][0][r][lane] = l + ev;   // A_mul
            sX[w][1][r][lane] = l * ev;   // L_mul * E
        }
        float acc[8];
        float bb = sB[lane];
#pragma unroll
        for (int r = 0; r < 8; r++) acc[r] = bb;

        for (int k = 0; k < 64; k += 4) {
            float w1a = sW1[(k + 0) * 64 + lane];
            float w1b = sW1[(k + 1) * 64 + lane];
            float w1c = sW1[(k + 2) * 64 + lane];
            float w1d = sW1[(k + 3) * 64 + lane];
            float w2a = sW2[(k + 0) * 64 + lane];
            float w2b = sW2[(k + 1) * 64 + lane];
            float w2c = sW2[(k + 2) * 64 + lane];
            float w2d = sW2[(k + 3) * 64 + lane];
#pragma unroll
            for (int r = 0; r < 8; r++) {
                float4 x1 = *(const float4*)&sX[w][0][r][k];
                float4 x2 = *(const float4*)&sX[w][1][r][k];
                acc[r] += x1.x * w1a + x1.y * w1b + x1.z * w1c + x1.w * w1d +
                          x2.x * w2a + x2.y * w2b + x2.z * w2c + x2.w * w2d;
            }
        }
#pragma unroll
        for (int r = 0; r < 8; r++) {
            int row = rowbase + r;
            float y = acc[r];
            y = (y > 0.f) ? y : 0.2f * y;
            float ss = y * y;
#pragma unroll
            for (int off = 32; off >= 1; off >>= 1) ss += __shfl_xor(ss, off, 64);
            float nrm = fmaxf(sqrtf(ss), EPS_F);
            Ebf[row * D + lane] = f32_to_bf16(y);
            all_e[(size_t)row * 256 + col_off + lane] = y / nrm;
        }
    }
}

// ---------------- scoring: one wave per sample, per-sample partials (NO atomics)
__device__ __forceinline__ float dot4(float4 a, float4 b) {
    return a.x * b.x + a.y * b.y + a.z * b.z + a.w * b.w;
}

__global__ __launch_bounds__(256) void score_kernel(const float* __restrict__ all_e,
                                                    const int* __restrict__ users,
                                                    const int* __restrict__ pos,
                                                    const int* __restrict__ neg,
                                                    float4* __restrict__ partials) {
    int wid = (blockIdx.x * blockDim.x + threadIdx.x) >> 6;
    int lane = threadIdx.x & 63;
    if (wid >= BATCH) return;
    int ui = users[wid];
    int pi = pos[wid];
    int ni = neg[wid];
    const float4* uv4 = (const float4*)(all_e + (size_t)ui * 256);
    const float4* pv4 = (const float4*)(all_e + (size_t)pi * 256);
    const float4* nv4 = (const float4*)(all_e + (size_t)ni * 256);
    float4 uv = uv4[lane];
    float4 pv = pv4[lane];
    float4 nv = nv4[lane];
    float s_up = dot4(uv, pv);
    float s_un = dot4(uv, nv);
    float s_uu = dot4(uv, uv);
    float s_pp = dot4(pv, pv);
    float s_nn = dot4(nv, nv);
#pragma unroll
    for (int off = 32; off >= 1; off >>= 1) {
        s_up += __shfl_xor(s_up, off, 64);
        s_un += __shfl_xor(s_un, off, 64);
        s_uu += __shfl_xor(s_uu, off, 64);
        s_pp += __shfl_xor(s_pp, off, 64);
        s_nn += __shfl_xor(s_nn, off, 64);
    }
    if (lane == 0) {
        float x = s_up - s_un;
        float ls = fminf(x, 0.f) - log1pf(expf(-fabsf(x)));  // log_sigmoid
        partials[wid] = make_float4(-ls, s_uu, s_pp, s_nn);
    }
}

// single-block tree reduction over 4096 float4 partials + final scalar
__global__ __launch_bounds__(256) void reduce_finalize(const float4* __restrict__ partials,
                                                       float* __restrict__ out) {
    __shared__ float4 s[256];
    int t = threadIdx.x;
    float4 a = make_float4(0.f, 0.f, 0.f, 0.f);
    for (int i = t; i < BATCH; i += 256) {
        float4 p = partials[i];
        a.x += p.x; a.y += p.y; a.z += p.z; a.w += p.w;
    }
    s[t] = a;
    __syncthreads();
    for (int off = 128; off >= 1; off >>= 1) {
        if (t < off) {
            s[t].x += s[t + off].x;
            s[t].y += s[t + off].y;
            s[t].z += s[t + off].z;
            s[t].w += s[t + off].w;
        }
        __syncthreads();
    }
    if (t == 0) {
        float bpr = s[0].x / (float)BATCH;
        float l2norm = (s[0].y + s[0].z + sqrtf(s[0].w)) * 0.5f;
        out[0] = bpr + L2_REG_F * l2norm / (float)BATCH;
    }
}

extern "C" void kernel_launch(void* const* d_in, const int* in_sizes, int n_in,
                              void* d_out, int out_size, void* d_ws, size_t ws_size,
                              hipStream_t stream) {
    const int* users = (const int*)d_in[0];
    const int* pos_items = (const int*)d_in[1];
    const int* neg_items = (const int*)d_in[2];
    const int* rows = (const int*)d_in[3];
    const int* cols = (const int*)d_in[4];
    const float* vals = (const float*)d_in[5];
    const float* user_embed = (const float*)d_in[6];
    const float* item_embed = (const float*)d_in[7];
    const float* W1 = (const float*)d_in[8];
    const float* b1 = (const float*)d_in[9];
    const float* W2 = (const float*)d_in[10];
    const float* b2 = (const float*)d_in[11];
    float* out = (float*)d_out;

    char* ws = (char*)d_ws;
    // workspace layout (128B-aligned chunks), total ~167 MB
    size_t off_alle = 0;                                     // 102,400,000
    size_t off_Lm = off_alle + (size_t)N_CNT * 256 * 4;      // 25,600,000
    size_t off_packed = off_Lm + (size_t)N_CNT * D * 4;      // 25,600,000
    size_t off_Ebf = off_packed + (size_t)NNZ_CNT * 8;       // 12,800,000
    size_t off_rowptr = off_Ebf + (size_t)N_CNT * D * 2;     // 400,128
    size_t off_counts = off_rowptr + 400128;                 // 400,128
    size_t off_blks = off_counts + 400128;                   // 2,048
    size_t off_bcur = off_blks + 2048;                       // 25,088 (391 cursors, 64B apart)
    size_t off_part = off_bcur + 25088;                      // 65,536

    float* all_e = (float*)(ws + off_alle);
    float2* bbuf = (float2*)(ws + off_alle);   // aliases all_e; dead before init_E runs
    float* Lm = (float*)(ws + off_Lm);
    float2* packed = (float2*)(ws + off_packed);
    unsigned short* Ebf = (unsigned short*)(ws + off_Ebf);
    int* row_ptr = (int*)(ws + off_rowptr);
    int* counts = (int*)(ws + off_counts);
    int* blk_sums = (int*)(ws + off_blks);
    int* bcur = (int*)(ws + off_bcur);
    float4* partials = (float4*)(ws + off_part);

    hipMemsetAsync(counts, 0, (size_t)N_CNT * 4, stream);

    // CSR build (bucketed two-phase scatter)
    hist_rows<<<(NNZ_CNT + 255) / 256, 256, 0, stream>>>(rows, counts);
    scan_phase1<<<SCAN_NBLK, 256, 0, stream>>>(counts, blk_sums);
    scan_phase2<<<1, 512, 0, stream>>>(blk_sums, row_ptr);
    scan_phase3<<<SCAN_NBLK, 256, 0, stream>>>(counts, blk_sums, row_ptr);
    binit<<<2, 256, 0, stream>>>(row_ptr, bcur);
    bucket_append<<<(NNZ_CNT + 255) / 256, 256, 0, stream>>>(rows, cols, vals, bcur, bbuf);
    csr_finalize<<<NBUCKET, 256, 0, stream>>>(bbuf, row_ptr, packed);

    // embeddings (after csr_finalize: bbuf aliases all_e)
    init_E<<<(N_CNT * D) / 256, 256, 0, stream>>>(user_embed, item_embed, Ebf, all_e);

    for (int l = 0; l < LAYERS; l++) {
        spmm_bf16<<<(N_CNT * 64) / 256, 256, 0, stream>>>(packed, row_ptr, Ebf, Lm);
        layer_fused<<<1024, 256, 0, stream>>>(Lm, Ebf, W1 + (size_t)l * 4096, b1 + (size_t)l * 64,
                                              W2 + (size_t)l * 4096, b2 + (size_t)l * 64,
                                              all_e, l);
    }

    score_kernel<<<(BATCH * 64) / 256, 256, 0, stream>>>(all_e, users, pos_items, neg_items,
                                                         partials);
    reduce_finalize<<<1, 256, 0, stream>>>(partials, out);
}

// Round 4
// 1016.540 us; speedup vs baseline: 1.3156x; 1.0753x over previous
//
#include <hip/hip_runtime.h>
#include <hip/hip_bf16.h>
#include <math.h>

#define U_CNT 50000
#define I_CNT 50000
#define N_CNT 100000
#define D 64
#define NNZ_CNT 3200000
#define LAYERS 3
#define BATCH 4096
#define L2_REG_F 1e-5f
#define EPS_F 1e-12f

#define SCAN_NBLK 391   // ceil(100000/256) for row_ptr scan
#define NBUCKET 391     // 256 rows per bucket
#define SC_NBLK 320     // scatter blocks
#define SC_CHUNK 10000  // NNZ / SC_NBLK
#define BCNT_N (NBUCKET * SC_NBLK)      // 125,120
#define BCNT_NBLK ((BCNT_N + 255) / 256) // 489

__device__ __forceinline__ unsigned short f32_to_bf16(float f) {
    unsigned int u = __float_as_uint(f);
    u += 0x7FFFu + ((u >> 16) & 1u);   // round-to-nearest-even
    return (unsigned short)(u >> 16);
}
__device__ __forceinline__ float bf16_to_f32(unsigned short h) {
    return __uint_as_float(((unsigned int)h) << 16);
}

// ---------------- init: all_e[:,0:64] = concat(ue,ie) fp32; E_bf = bf16 copy
__global__ void init_E(const float* __restrict__ ue, const float* __restrict__ ie,
                       unsigned short* __restrict__ Ebf, float* __restrict__ all_e) {
    int tid = blockIdx.x * blockDim.x + threadIdx.x;
    if (tid >= N_CNT * D) return;
    int row = tid >> 6;
    int d = tid & 63;
    float v = (row < U_CNT) ? ue[tid] : ie[tid - U_CNT * D];
    Ebf[tid] = f32_to_bf16(v);
    all_e[(size_t)row * 256 + d] = v;
}

// ---------------- per-row histogram (for row_ptr)
__global__ void hist_rows(const int* __restrict__ rows, int* __restrict__ counts) {
    int e = blockIdx.x * blockDim.x + threadIdx.x;
    if (e < NNZ_CNT) atomicAdd(&counts[rows[e]], 1);
}

// ---------------- generic hierarchical exclusive scan (n <= 512*256)
__global__ void scan_p1(const int* __restrict__ in, int* __restrict__ bsums, int n) {
    __shared__ int s[256];
    int t = threadIdx.x;
    int i = blockIdx.x * 256 + t;
    int v = (i < n) ? in[i] : 0;
    s[t] = v;
    __syncthreads();
    for (int off = 128; off >= 1; off >>= 1) {
        if (t < off) s[t] += s[t + off];
        __syncthreads();
    }
    if (t == 0) bsums[blockIdx.x] = s[0];
}

// exclusive scan of block sums (nblk <= 512); optionally writes *tail_ptr = tail_val
__global__ void scan_p2(int* __restrict__ bsums, int nblk, int* tail_ptr, int tail_val) {
    __shared__ int s[512];
    int t = threadIdx.x;
    int v = (t < nblk) ? bsums[t] : 0;
    s[t] = v;
    __syncthreads();
    for (int off = 1; off < 512; off <<= 1) {
        int x = (t >= off) ? s[t - off] : 0;
        __syncthreads();
        s[t] += x;
        __syncthreads();
    }
    if (t < nblk) bsums[t] = s[t] - v;  // exclusive
    if (t == 0 && tail_ptr) *tail_ptr = tail_val;
}

// per-chunk exclusive scan + block offset; in-place (out may alias in) is safe
__global__ void scan_p3(const int* __restrict__ in, const int* __restrict__ bsums,
                        int* __restrict__ out, int n) {
    __shared__ int s[256];
    int t = threadIdx.x;
    int i = blockIdx.x * 256 + t;
    int v = (i < n) ? in[i] : 0;
    s[t] = v;
    __syncthreads();
    for (int off = 1; off < 256; off <<= 1) {
        int x = (t >= off) ? s[t - off] : 0;
        __syncthreads();
        s[t] += x;
        __syncthreads();
    }
    if (i < n) out[i] = s[t] - v + bsums[blockIdx.x];
}

// ---------------- phase 1a: per-block bucket histogram -> bcnt[bucket*SC_NBLK + blk]
__global__ __launch_bounds__(256) void bucket_hist(const int* __restrict__ rows,
                                                   int* __restrict__ bcnt) {
    __shared__ int h[NBUCKET];
    int blk = blockIdx.x, t = threadIdx.x;
    for (int b = t; b < NBUCKET; b += 256) h[b] = 0;
    __syncthreads();
    int s = blk * SC_CHUNK, e = s + SC_CHUNK;
    for (int i = s + t; i < e; i += 256) atomicAdd(&h[rows[i] >> 8], 1);
    __syncthreads();
    for (int b = t; b < NBUCKET; b += 256) bcnt[b * SC_NBLK + blk] = h[b];
}

// ---------------- phase 1b: scatter into per-(bucket,block) EXCLUSIVE regions.
// LDS cursors (no global atomics); each output cache line is written by one block only,
// so stores merge in that XCD's L2 -> no cross-XCD line ping-pong.
__global__ __launch_bounds__(256) void block_scatter(const int* __restrict__ rows,
                                                     const int* __restrict__ cols,
                                                     const float* __restrict__ vals,
                                                     const int* __restrict__ boff,
                                                     float2* __restrict__ bbuf) {
    __shared__ int cur[NBUCKET];
    int blk = blockIdx.x, t = threadIdx.x;
    for (int b = t; b < NBUCKET; b += 256) cur[b] = boff[b * SC_NBLK + blk];
    __syncthreads();
    int s = blk * SC_CHUNK, e = s + SC_CHUNK;
    for (int i = s + t; i < e; i += 256) {
        int r = rows[i];
        int b = r >> 8;
        int p = atomicAdd(&cur[b], 1);
        unsigned int bits = ((unsigned int)(r & 255) << 17) | (unsigned int)cols[i];
        bbuf[p] = make_float2(vals[i], __uint_as_float(bits));
    }
}

// phase 2: per-bucket CSR finalize with LDS row cursors; bucket region exclusive to block
__global__ __launch_bounds__(256) void csr_finalize(const float2* __restrict__ bbuf,
                                                    const int* __restrict__ row_ptr,
                                                    float2* __restrict__ packed) {
    __shared__ int cur[256];
    int base = blockIdx.x << 8;
    int hi = min(base + 256, N_CNT);
    int t = threadIdx.x;
    if (base + t < hi) cur[t] = row_ptr[base + t];
    __syncthreads();
    int s = row_ptr[base];
    int e = row_ptr[hi];
    for (int i = s + t; i < e; i += 256) {
        float2 rec = bbuf[i];
        unsigned int bits = __float_as_uint(rec.y);
        int rl = bits >> 17;
        int c = (int)(bits & 0x1FFFFu);
        int p = atomicAdd(&cur[rl], 1);
        packed[p] = make_float2(rec.x, __int_as_float(c));
    }
}

// ---------------- SpMM: one wave per row; 2 edges/iter (half-wave each), bf16 E gathers
__global__ __launch_bounds__(256) void spmm_bf16(const float2* __restrict__ packed,
                                                 const int* __restrict__ row_ptr,
                                                 const unsigned short* __restrict__ Ebf,
                                                 float* __restrict__ Lm) {
    int wid = (blockIdx.x * blockDim.x + threadIdx.x) >> 6;
    int lane = threadIdx.x & 63;
    if (wid >= N_CNT) return;
    int s = row_ptr[wid];
    int e = row_ptr[wid + 1];
    int half = lane >> 5;   // which edge of the pair
    int hl = lane & 31;     // dim pair: handles dims 2*hl, 2*hl+1
    float acc0 = 0.f, acc1 = 0.f;
    for (int i = s + half; i < e; i += 2) {
        float2 rec = packed[i];
        int c = __float_as_int(rec.y);
        unsigned int ev = *(const unsigned int*)(Ebf + (size_t)c * D + 2 * hl);
        float e0 = __uint_as_float((ev & 0xFFFFu) << 16);
        float e1 = __uint_as_float(ev & 0xFFFF0000u);
        acc0 += rec.x * e0;
        acc1 += rec.x * e1;
    }
    acc0 += __shfl_xor(acc0, 32, 64);
    acc1 += __shfl_xor(acc1, 32, 64);
    if (half == 0) {
        *(float2*)(Lm + (size_t)wid * D + 2 * hl) = make_float2(acc0, acc1);
    }
}

// ---------------- fused layer: x1 = Lm + E, x2 = Lm*E ; y = leaky(x1@W1 + x2@W2 + b1+b2)
// un-normalized y -> E_bf (bf16), normalized y -> all_e[:, (layer+1)*64:...]
#define TILE_ROWS 32  // 4 waves * 8 rows
__global__ __launch_bounds__(256) void layer_fused(const float* __restrict__ Lm,
                                                   unsigned short* __restrict__ Ebf,
                                                   const float* __restrict__ W1,
                                                   const float* __restrict__ b1,
                                                   const float* __restrict__ W2,
                                                   const float* __restrict__ b2,
                                                   float* __restrict__ all_e, int layer) {
    __shared__ float sW1[64 * 64];
    __shared__ float sW2[64 * 64];
    __shared__ float sB[64];
    __shared__ float sX[4][2][8][64];  // wave-private staging

    int t = threadIdx.x;
    for (int i = t; i < 4096; i += 256) {
        sW1[i] = W1[i];
        sW2[i] = W2[i];
    }
    if (t < 64) sB[t] = b1[t] + b2[t];
    __syncthreads();

    int w = t >> 6;
    int lane = t & 63;
    int col_off = (layer + 1) * 64;

    for (int tile = blockIdx.x; tile < N_CNT / TILE_ROWS; tile += gridDim.x) {
        int rowbase = tile * TILE_ROWS + w * 8;
#pragma unroll
        for (int r = 0; r < 8; r++) {
            int row = rowbase + r;
            float l = Lm[row * D + lane];
            float ev = bf16_to_f32(Ebf[row * D + lane]);
            sX[w][0][r][lane] = l + ev;   // A_mul
            sX[w][1][r][lane] = l * ev;   // L_mul * E
        }
        float acc[8];
        float bb = sB[lane];
#pragma unroll
        for (int r = 0; r < 8; r++) acc[r] = bb;

        for (int k = 0; k < 64; k += 4) {
            float w1a = sW1[(k + 0) * 64 + lane];
            float w1b = sW1[(k + 1) * 64 + lane];
            float w1c = sW1[(k + 2) * 64 + lane];
            float w1d = sW1[(k + 3) * 64 + lane];
            float w2a = sW2[(k + 0) * 64 + lane];
            float w2b = sW2[(k + 1) * 64 + lane];
            float w2c = sW2[(k + 2) * 64 + lane];
            float w2d = sW2[(k + 3) * 64 + lane];
#pragma unroll
            for (int r = 0; r < 8; r++) {
                float4 x1 = *(const float4*)&sX[w][0][r][k];
                float4 x2 = *(const float4*)&sX[w][1][r][k];
                acc[r] += x1.x * w1a + x1.y * w1b + x1.z * w1c + x1.w * w1d +
                          x2.x * w2a + x2.y * w2b + x2.z * w2c + x2.w * w2d;
            }
        }
#pragma unroll
        for (int r = 0; r < 8; r++) {
            int row = rowbase + r;
            float y = acc[r];
            y = (y > 0.f) ? y : 0.2f * y;
            float ss = y * y;
#pragma unroll
            for (int off = 32; off >= 1; off >>= 1) ss += __shfl_xor(ss, off, 64);
            float nrm = fmaxf(sqrtf(ss), EPS_F);
            Ebf[row * D + lane] = f32_to_bf16(y);
            all_e[(size_t)row * 256 + col_off + lane] = y / nrm;
        }
    }
}

// ---------------- scoring: one wave per sample, per-sample partials (NO atomics)
__device__ __forceinline__ float dot4(float4 a, float4 b) {
    return a.x * b.x + a.y * b.y + a.z * b.z + a.w * b.w;
}

__global__ __launch_bounds__(256) void score_kernel(const float* __restrict__ all_e,
                                                    const int* __restrict__ users,
                                                    const int* __restrict__ pos,
                                                    const int* __restrict__ neg,
                                                    float4* __restrict__ partials) {
    int wid = (blockIdx.x * blockDim.x + threadIdx.x) >> 6;
    int lane = threadIdx.x & 63;
    if (wid >= BATCH) return;
    int ui = users[wid];
    int pi = pos[wid];
    int ni = neg[wid];
    const float4* uv4 = (const float4*)(all_e + (size_t)ui * 256);
    const float4* pv4 = (const float4*)(all_e + (size_t)pi * 256);
    const float4* nv4 = (const float4*)(all_e + (size_t)ni * 256);
    float4 uv = uv4[lane];
    float4 pv = pv4[lane];
    float4 nv = nv4[lane];
    float s_up = dot4(uv, pv);
    float s_un = dot4(uv, nv);
    float s_uu = dot4(uv, uv);
    float s_pp = dot4(pv, pv);
    float s_nn = dot4(nv, nv);
#pragma unroll
    for (int off = 32; off >= 1; off >>= 1) {
        s_up += __shfl_xor(s_up, off, 64);
        s_un += __shfl_xor(s_un, off, 64);
        s_uu += __shfl_xor(s_uu, off, 64);
        s_pp += __shfl_xor(s_pp, off, 64);
        s_nn += __shfl_xor(s_nn, off, 64);
    }
    if (lane == 0) {
        float x = s_up - s_un;
        float ls = fminf(x, 0.f) - log1pf(expf(-fabsf(x)));  // log_sigmoid
        partials[wid] = make_float4(-ls, s_uu, s_pp, s_nn);
    }
}

// single-block tree reduction over 4096 float4 partials + final scalar
__global__ __launch_bounds__(256) void reduce_finalize(const float4* __restrict__ partials,
                                                       float* __restrict__ out) {
    __shared__ float4 s[256];
    int t = threadIdx.x;
    float4 a = make_float4(0.f, 0.f, 0.f, 0.f);
    for (int i = t; i < BATCH; i += 256) {
        float4 p = partials[i];
        a.x += p.x; a.y += p.y; a.z += p.z; a.w += p.w;
    }
    s[t] = a;
    __syncthreads();
    for (int off = 128; off >= 1; off >>= 1) {
        if (t < off) {
            s[t].x += s[t + off].x;
            s[t].y += s[t + off].y;
            s[t].z += s[t + off].z;
            s[t].w += s[t + off].w;
        }
        __syncthreads();
    }
    if (t == 0) {
        float bpr = s[0].x / (float)BATCH;
        float l2norm = (s[0].y + s[0].z + sqrtf(s[0].w)) * 0.5f;
        out[0] = bpr + L2_REG_F * l2norm / (float)BATCH;
    }
}

extern "C" void kernel_launch(void* const* d_in, const int* in_sizes, int n_in,
                              void* d_out, int out_size, void* d_ws, size_t ws_size,
                              hipStream_t stream) {
    const int* users = (const int*)d_in[0];
    const int* pos_items = (const int*)d_in[1];
    const int* neg_items = (const int*)d_in[2];
    const int* rows = (const int*)d_in[3];
    const int* cols = (const int*)d_in[4];
    const float* vals = (const float*)d_in[5];
    const float* user_embed = (const float*)d_in[6];
    const float* item_embed = (const float*)d_in[7];
    const float* W1 = (const float*)d_in[8];
    const float* b1 = (const float*)d_in[9];
    const float* W2 = (const float*)d_in[10];
    const float* b2 = (const float*)d_in[11];
    float* out = (float*)d_out;

    char* ws = (char*)d_ws;
    // workspace layout, total ~168 MB
    size_t off_alle = 0;                                     // 102,400,000
    size_t off_Lm = off_alle + (size_t)N_CNT * 256 * 4;      // 25,600,000
    size_t off_packed = off_Lm + (size_t)N_CNT * D * 4;      // 25,600,000
    size_t off_Ebf = off_packed + (size_t)NNZ_CNT * 8;       // 12,800,000
    size_t off_rowptr = off_Ebf + (size_t)N_CNT * D * 2;     // 400,128
    size_t off_counts = off_rowptr + 400128;                 // 400,128
    size_t off_blkA = off_counts + 400128;                   // 2,048 (391 block sums)
    size_t off_blkB = off_blkA + 2048;                       // 2,048 (489 block sums)
    size_t off_bcnt = off_blkB + 2048;                       // 500,480 (391*320 ints)
    size_t off_part = off_bcnt + 500480;                     // 65,536

    float* all_e = (float*)(ws + off_alle);
    float2* bbuf = (float2*)(ws + off_alle);   // aliases all_e; dead before init_E runs
    float* Lm = (float*)(ws + off_Lm);
    float2* packed = (float2*)(ws + off_packed);
    unsigned short* Ebf = (unsigned short*)(ws + off_Ebf);
    int* row_ptr = (int*)(ws + off_rowptr);
    int* counts = (int*)(ws + off_counts);
    int* blkA = (int*)(ws + off_blkA);
    int* blkB = (int*)(ws + off_blkB);
    int* bcnt = (int*)(ws + off_bcnt);
    float4* partials = (float4*)(ws + off_part);

    hipMemsetAsync(counts, 0, (size_t)N_CNT * 4, stream);

    // row_ptr (per-row CSR offsets)
    hist_rows<<<(NNZ_CNT + 255) / 256, 256, 0, stream>>>(rows, counts);
    scan_p1<<<SCAN_NBLK, 256, 0, stream>>>(counts, blkA, N_CNT);
    scan_p2<<<1, 512, 0, stream>>>(blkA, SCAN_NBLK, row_ptr + N_CNT, NNZ_CNT);
    scan_p3<<<SCAN_NBLK, 256, 0, stream>>>(counts, blkA, row_ptr, N_CNT);

    // bucketed multisplit with exclusive per-(bucket,block) regions
    bucket_hist<<<SC_NBLK, 256, 0, stream>>>(rows, bcnt);
    scan_p1<<<BCNT_NBLK, 256, 0, stream>>>(bcnt, blkB, BCNT_N);
    scan_p2<<<1, 512, 0, stream>>>(blkB, BCNT_NBLK, (int*)nullptr, 0);
    scan_p3<<<BCNT_NBLK, 256, 0, stream>>>(bcnt, blkB, bcnt, BCNT_N);  // in-place
    block_scatter<<<SC_NBLK, 256, 0, stream>>>(rows, cols, vals, bcnt, bbuf);
    csr_finalize<<<NBUCKET, 256, 0, stream>>>(bbuf, row_ptr, packed);

    // embeddings (after csr_finalize: bbuf aliases all_e)
    init_E<<<(N_CNT * D) / 256, 256, 0, stream>>>(user_embed, item_embed, Ebf, all_e);

    for (int l = 0; l < LAYERS; l++) {
        spmm_bf16<<<(N_CNT * 64) / 256, 256, 0, stream>>>(packed, row_ptr, Ebf, Lm);
        layer_fused<<<1024, 256, 0, stream>>>(Lm, Ebf, W1 + (size_t)l * 4096, b1 + (size_t)l * 64,
                                              W2 + (size_t)l * 4096, b2 + (size_t)l * 64,
                                              all_e, l);
    }

    score_kernel<<<(BATCH * 64) / 256, 256, 0, stream>>>(all_e, users, pos_items, neg_items,
                                                         partials);
    reduce_finalize<<<1, 256, 0, stream>>>(partials, out);
}

// Round 5
// 651.229 us; speedup vs baseline: 2.0537x; 1.5610x over previous
//
#include <hip/hip_runtime.h>
#include <hip/hip_bf16.h>
#include <math.h>

#define U_CNT 50000
#define I_CNT 50000
#define N_CNT 100000
#define D 64
#define NNZ_CNT 3200000
#define LAYERS 3
#define BATCH 4096
#define L2_REG_F 1e-5f
#define EPS_F 1e-12f

#define NBUCKET 391     // 256 rows per bucket
#define SC_NBLK 320     // scatter blocks
#define SC_CHUNK 10000  // NNZ / SC_NBLK
#define BCNT_N (NBUCKET * SC_NBLK)       // 125,120
#define BCNT_NBLK ((BCNT_N + 255) / 256) // 489

__device__ __forceinline__ unsigned short f32_to_bf16(float f) {
    unsigned int u = __float_as_uint(f);
    u += 0x7FFFu + ((u >> 16) & 1u);   // round-to-nearest-even
    return (unsigned short)(u >> 16);
}
__device__ __forceinline__ float bf16_to_f32(unsigned short h) {
    return __uint_as_float(((unsigned int)h) << 16);
}

// ---------------- init: all_e[:,0:64] = concat(ue,ie) fp32; E_bf = bf16 copy
__global__ void init_E(const float* __restrict__ ue, const float* __restrict__ ie,
                       unsigned short* __restrict__ Ebf, float* __restrict__ all_e) {
    int tid = blockIdx.x * blockDim.x + threadIdx.x;
    if (tid >= N_CNT * D) return;
    int row = tid >> 6;
    int d = tid & 63;
    float v = (row < U_CNT) ? ue[tid] : ie[tid - U_CNT * D];
    Ebf[tid] = f32_to_bf16(v);
    all_e[(size_t)row * 256 + d] = v;
}

// ---------------- generic hierarchical exclusive scan (n <= 512*256)
__global__ void scan_p1(const int* __restrict__ in, int* __restrict__ bsums, int n) {
    __shared__ int s[256];
    int t = threadIdx.x;
    int i = blockIdx.x * 256 + t;
    int v = (i < n) ? in[i] : 0;
    s[t] = v;
    __syncthreads();
    for (int off = 128; off >= 1; off >>= 1) {
        if (t < off) s[t] += s[t + off];
        __syncthreads();
    }
    if (t == 0) bsums[blockIdx.x] = s[0];
}

__global__ void scan_p2(int* __restrict__ bsums, int nblk) {
    __shared__ int s[512];
    int t = threadIdx.x;
    int v = (t < nblk) ? bsums[t] : 0;
    s[t] = v;
    __syncthreads();
    for (int off = 1; off < 512; off <<= 1) {
        int x = (t >= off) ? s[t - off] : 0;
        __syncthreads();
        s[t] += x;
        __syncthreads();
    }
    if (t < nblk) bsums[t] = s[t] - v;  // exclusive
}

__global__ void scan_p3(const int* __restrict__ in, const int* __restrict__ bsums,
                        int* __restrict__ out, int n) {
    __shared__ int s[256];
    int t = threadIdx.x;
    int i = blockIdx.x * 256 + t;
    int v = (i < n) ? in[i] : 0;
    s[t] = v;
    __syncthreads();
    for (int off = 1; off < 256; off <<= 1) {
        int x = (t >= off) ? s[t - off] : 0;
        __syncthreads();
        s[t] += x;
        __syncthreads();
    }
    if (i < n) out[i] = s[t] - v + bsums[blockIdx.x];
}

// ---------------- per-block bucket histogram -> bcnt[bucket*SC_NBLK + blk]
__global__ __launch_bounds__(256) void bucket_hist(const int* __restrict__ rows,
                                                   int* __restrict__ bcnt) {
    __shared__ int h[NBUCKET];
    int blk = blockIdx.x, t = threadIdx.x;
    for (int b = t; b < NBUCKET; b += 256) h[b] = 0;
    __syncthreads();
    int s = blk * SC_CHUNK, e = s + SC_CHUNK;
    for (int i = s + t; i < e; i += 256) atomicAdd(&h[rows[i] >> 8], 1);
    __syncthreads();
    for (int b = t; b < NBUCKET; b += 256) bcnt[b * SC_NBLK + blk] = h[b];
}

// ---------------- scatter into per-(bucket,block) EXCLUSIVE regions (LDS cursors)
__global__ __launch_bounds__(256) void block_scatter(const int* __restrict__ rows,
                                                     const int* __restrict__ cols,
                                                     const float* __restrict__ vals,
                                                     const int* __restrict__ boff,
                                                     float2* __restrict__ bbuf) {
    __shared__ int cur[NBUCKET];
    int blk = blockIdx.x, t = threadIdx.x;
    for (int b = t; b < NBUCKET; b += 256) cur[b] = boff[b * SC_NBLK + blk];
    __syncthreads();
    int s = blk * SC_CHUNK, e = s + SC_CHUNK;
    for (int i = s + t; i < e; i += 256) {
        int r = rows[i];
        int b = r >> 8;
        int p = atomicAdd(&cur[b], 1);
        unsigned int bits = ((unsigned int)(r & 255) << 17) | (unsigned int)cols[i];
        bbuf[p] = make_float2(vals[i], __uint_as_float(bits));
    }
}

// ---------------- per-bucket: LDS rowlocal hist -> LDS scan -> row_ptr (coalesced,
// no global atomics) -> scatter into row-sorted `packed` with LDS cursors.
// bucket start in bbuf == row_ptr of the bucket's first row (bucket-major consistency).
__global__ __launch_bounds__(256) void csr_finalize(const float2* __restrict__ bbuf,
                                                    const int* __restrict__ boff,
                                                    int* __restrict__ row_ptr,
                                                    float2* __restrict__ packed) {
    __shared__ int h[256];
    __shared__ int cur[256];
    int b = blockIdx.x, t = threadIdx.x;
    int s = boff[b * SC_NBLK];
    int e = (b == NBUCKET - 1) ? NNZ_CNT : boff[(b + 1) * SC_NBLK];
    h[t] = 0;
    __syncthreads();
    for (int i = s + t; i < e; i += 256)
        atomicAdd(&h[__float_as_uint(bbuf[i].y) >> 17], 1);
    __syncthreads();
    int v = h[t];
    for (int off = 1; off < 256; off <<= 1) {   // Hillis-Steele inclusive scan
        int x = (t >= off) ? h[t - off] : 0;
        __syncthreads();
        h[t] += x;
        __syncthreads();
    }
    int start = s + h[t] - v;  // exclusive + bucket base
    int row = (b << 8) + t;
    if (row < N_CNT) row_ptr[row] = start;
    cur[t] = start;
    if (b == 0 && t == 0) row_ptr[N_CNT] = NNZ_CNT;
    __syncthreads();
    for (int i = s + t; i < e; i += 256) {
        float2 rec = bbuf[i];
        unsigned int bits = __float_as_uint(rec.y);
        int p = atomicAdd(&cur[bits >> 17], 1);
        packed[p] = make_float2(rec.x, __int_as_float(bits & 0x1FFFFu));
    }
}

// ---------------- SpMM: one wave per row; 4 subgroups x 16 lanes, each subgroup
// handles one edge per iter (4 independent gathers in flight) + prefetched metadata.
__global__ __launch_bounds__(256) void spmm_bf16(const float2* __restrict__ packed,
                                                 const int* __restrict__ row_ptr,
                                                 const unsigned short* __restrict__ Ebf,
                                                 float* __restrict__ Lm) {
    int wid = (blockIdx.x * blockDim.x + threadIdx.x) >> 6;
    int lane = threadIdx.x & 63;
    if (wid >= N_CNT) return;
    int s = row_ptr[wid];
    int e = row_ptr[wid + 1];
    int sub = lane >> 4;   // edge slot within group of 4
    int sl = lane & 15;    // covers dims 4*sl .. 4*sl+3
    float ax = 0.f, ay = 0.f, az = 0.f, aw = 0.f;
    int i = s + sub;
    float2 rec = (i < e) ? packed[i] : make_float2(0.f, __int_as_float(0));
    while (i < e) {
        int inext = i + 4;
        float2 rnext = (inext < e) ? packed[inext] : make_float2(0.f, __int_as_float(0));
        int c = __float_as_int(rec.y);
        ushort4 ev = *(const ushort4*)(Ebf + (size_t)c * D + 4 * sl);
        float v = rec.x;
        ax += v * bf16_to_f32(ev.x);
        ay += v * bf16_to_f32(ev.y);
        az += v * bf16_to_f32(ev.z);
        aw += v * bf16_to_f32(ev.w);
        rec = rnext;
        i = inext;
    }
    // sum the 4 edge-slot partials (lanes sl, sl+16, sl+32, sl+48)
    ax += __shfl_xor(ax, 32, 64); ay += __shfl_xor(ay, 32, 64);
    az += __shfl_xor(az, 32, 64); aw += __shfl_xor(aw, 32, 64);
    ax += __shfl_xor(ax, 16, 64); ay += __shfl_xor(ay, 16, 64);
    az += __shfl_xor(az, 16, 64); aw += __shfl_xor(aw, 16, 64);
    if (sub == 0) {
        *(float4*)(Lm + (size_t)wid * D + 4 * sl) = make_float4(ax, ay, az, aw);
    }
}

// ---------------- fused layer: x1 = Lm + E, x2 = Lm*E ; y = leaky(x1@W1 + x2@W2 + b1+b2)
// un-normalized y -> E_bf (bf16), normalized y -> all_e[:, (layer+1)*64:...]
#define TILE_ROWS 32  // 4 waves * 8 rows
__global__ __launch_bounds__(256) void layer_fused(const float* __restrict__ Lm,
                                                   unsigned short* __restrict__ Ebf,
                                                   const float* __restrict__ W1,
                                                   const float* __restrict__ b1,
                                                   const float* __restrict__ W2,
                                                   const float* __restrict__ b2,
                                                   float* __restrict__ all_e, int layer) {
    __shared__ float sW1[64 * 64];
    __shared__ float sW2[64 * 64];
    __shared__ float sB[64];
    __shared__ float sX[4][2][8][64];  // wave-private staging

    int t = threadIdx.x;
    for (int i = t; i < 4096; i += 256) {
        sW1[i] = W1[i];
        sW2[i] = W2[i];
    }
    if (t < 64) sB[t] = b1[t] + b2[t];
    __syncthreads();

    int w = t >> 6;
    int lane = t & 63;
    int col_off = (layer + 1) * 64;

    for (int tile = blockIdx.x; tile < N_CNT / TILE_ROWS; tile += gridDim.x) {
        int rowbase = tile * TILE_ROWS + w * 8;
#pragma unroll
        for (int r = 0; r < 8; r++) {
            int row = rowbase + r;
            float l = Lm[row * D + lane];
            float ev = bf16_to_f32(Ebf[row * D + lane]);
            sX[w][0][r][lane] = l + ev;   // A_mul
            sX[w][1][r][lane] = l * ev;   // L_mul * E
        }
        float acc[8];
        float bb = sB[lane];
#pragma unroll
        for (int r = 0; r < 8; r++) acc[r] = bb;

        for (int k = 0; k < 64; k += 4) {
            float w1a = sW1[(k + 0) * 64 + lane];
            float w1b = sW1[(k + 1) * 64 + lane];
            float w1c = sW1[(k + 2) * 64 + lane];
            float w1d = sW1[(k + 3) * 64 + lane];
            float w2a = sW2[(k + 0) * 64 + lane];
            float w2b = sW2[(k + 1) * 64 + lane];
            float w2c = sW2[(k + 2) * 64 + lane];
            float w2d = sW2[(k + 3) * 64 + lane];
#pragma unroll
            for (int r = 0; r < 8; r++) {
                float4 x1 = *(const float4*)&sX[w][0][r][k];
                float4 x2 = *(const float4*)&sX[w][1][r][k];
                acc[r] += x1.x * w1a + x1.y * w1b + x1.z * w1c + x1.w * w1d +
                          x2.x * w2a + x2.y * w2b + x2.z * w2c + x2.w * w2d;
            }
        }
#pragma unroll
        for (int r = 0; r < 8; r++) {
            int row = rowbase + r;
            float y = acc[r];
            y = (y > 0.f) ? y : 0.2f * y;
            float ss = y * y;
#pragma unroll
            for (int off = 32; off >= 1; off >>= 1) ss += __shfl_xor(ss, off, 64);
            float nrm = fmaxf(sqrtf(ss), EPS_F);
            Ebf[row * D + lane] = f32_to_bf16(y);
            all_e[(size_t)row * 256 + col_off + lane] = y / nrm;
        }
    }
}

// ---------------- scoring: one wave per sample, per-sample partials (NO atomics)
__device__ __forceinline__ float dot4(float4 a, float4 b) {
    return a.x * b.x + a.y * b.y + a.z * b.z + a.w * b.w;
}

__global__ __launch_bounds__(256) void score_kernel(const float* __restrict__ all_e,
                                                    const int* __restrict__ users,
                                                    const int* __restrict__ pos,
                                                    const int* __restrict__ neg,
                                                    float4* __restrict__ partials) {
    int wid = (blockIdx.x * blockDim.x + threadIdx.x) >> 6;
    int lane = threadIdx.x & 63;
    if (wid >= BATCH) return;
    int ui = users[wid];
    int pi = pos[wid];
    int ni = neg[wid];
    const float4* uv4 = (const float4*)(all_e + (size_t)ui * 256);
    const float4* pv4 = (const float4*)(all_e + (size_t)pi * 256);
    const float4* nv4 = (const float4*)(all_e + (size_t)ni * 256);
    float4 uv = uv4[lane];
    float4 pv = pv4[lane];
    float4 nv = nv4[lane];
    float s_up = dot4(uv, pv);
    float s_un = dot4(uv, nv);
    float s_uu = dot4(uv, uv);
    float s_pp = dot4(pv, pv);
    float s_nn = dot4(nv, nv);
#pragma unroll
    for (int off = 32; off >= 1; off >>= 1) {
        s_up += __shfl_xor(s_up, off, 64);
        s_un += __shfl_xor(s_un, off, 64);
        s_uu += __shfl_xor(s_uu, off, 64);
        s_pp += __shfl_xor(s_pp, off, 64);
        s_nn += __shfl_xor(s_nn, off, 64);
    }
    if (lane == 0) {
        float x = s_up - s_un;
        float ls = fminf(x, 0.f) - log1pf(expf(-fabsf(x)));  // log_sigmoid
        partials[wid] = make_float4(-ls, s_uu, s_pp, s_nn);
    }
}

// single-block tree reduction over 4096 float4 partials + final scalar
__global__ __launch_bounds__(256) void reduce_finalize(const float4* __restrict__ partials,
                                                       float* __restrict__ out) {
    __shared__ float4 s[256];
    int t = threadIdx.x;
    float4 a = make_float4(0.f, 0.f, 0.f, 0.f);
    for (int i = t; i < BATCH; i += 256) {
        float4 p = partials[i];
        a.x += p.x; a.y += p.y; a.z += p.z; a.w += p.w;
    }
    s[t] = a;
    __syncthreads();
    for (int off = 128; off >= 1; off >>= 1) {
        if (t < off) {
            s[t].x += s[t + off].x;
            s[t].y += s[t + off].y;
            s[t].z += s[t + off].z;
            s[t].w += s[t + off].w;
        }
        __syncthreads();
    }
    if (t == 0) {
        float bpr = s[0].x / (float)BATCH;
        float l2norm = (s[0].y + s[0].z + sqrtf(s[0].w)) * 0.5f;
        out[0] = bpr + L2_REG_F * l2norm / (float)BATCH;
    }
}

extern "C" void kernel_launch(void* const* d_in, const int* in_sizes, int n_in,
                              void* d_out, int out_size, void* d_ws, size_t ws_size,
                              hipStream_t stream) {
    const int* users = (const int*)d_in[0];
    const int* pos_items = (const int*)d_in[1];
    const int* neg_items = (const int*)d_in[2];
    const int* rows = (const int*)d_in[3];
    const int* cols = (const int*)d_in[4];
    const float* vals = (const float*)d_in[5];
    const float* user_embed = (const float*)d_in[6];
    const float* item_embed = (const float*)d_in[7];
    const float* W1 = (const float*)d_in[8];
    const float* b1 = (const float*)d_in[9];
    const float* W2 = (const float*)d_in[10];
    const float* b2 = (const float*)d_in[11];
    float* out = (float*)d_out;

    char* ws = (char*)d_ws;
    // workspace layout, total ~168 MB
    size_t off_alle = 0;                                     // 102,400,000
    size_t off_Lm = off_alle + (size_t)N_CNT * 256 * 4;      // 25,600,000
    size_t off_packed = off_Lm + (size_t)N_CNT * D * 4;      // 25,600,000
    size_t off_Ebf = off_packed + (size_t)NNZ_CNT * 8;       // 12,800,000
    size_t off_rowptr = off_Ebf + (size_t)N_CNT * D * 2;     // 400,128
    size_t off_blkB = off_rowptr + 400128;                   // 2,048 (489 block sums)
    size_t off_bcnt = off_blkB + 2048;                       // 500,480 (391*320 ints)
    size_t off_part = off_bcnt + 500480;                     // 65,536

    float* all_e = (float*)(ws + off_alle);
    float2* bbuf = (float2*)(ws + off_alle);   // aliases all_e; dead before init_E runs
    float* Lm = (float*)(ws + off_Lm);
    float2* packed = (float2*)(ws + off_packed);
    unsigned short* Ebf = (unsigned short*)(ws + off_Ebf);
    int* row_ptr = (int*)(ws + off_rowptr);
    int* blkB = (int*)(ws + off_blkB);
    int* bcnt = (int*)(ws + off_bcnt);
    float4* partials = (float4*)(ws + off_part);

    // bucketed multisplit with exclusive per-(bucket,block) regions
    bucket_hist<<<SC_NBLK, 256, 0, stream>>>(rows, bcnt);
    scan_p1<<<BCNT_NBLK, 256, 0, stream>>>(bcnt, blkB, BCNT_N);
    scan_p2<<<1, 512, 0, stream>>>(blkB, BCNT_NBLK);
    scan_p3<<<BCNT_NBLK, 256, 0, stream>>>(bcnt, blkB, bcnt, BCNT_N);  // in-place
    block_scatter<<<SC_NBLK, 256, 0, stream>>>(rows, cols, vals, bcnt, bbuf);
    // row_ptr + row-sorted packed, all from the bucketed buffer (no global atomics)
    csr_finalize<<<NBUCKET, 256, 0, stream>>>(bbuf, bcnt, row_ptr, packed);

    // embeddings (after csr_finalize: bbuf aliases all_e)
    init_E<<<(N_CNT * D) / 256, 256, 0, stream>>>(user_embed, item_embed, Ebf, all_e);

    for (int l = 0; l < LAYERS; l++) {
        spmm_bf16<<<(N_CNT * 64) / 256, 256, 0, stream>>>(packed, row_ptr, Ebf, Lm);
        layer_fused<<<1024, 256, 0, stream>>>(Lm, Ebf, W1 + (size_t)l * 4096, b1 + (size_t)l * 64,
                                              W2 + (size_t)l * 4096, b2 + (size_t)l * 64,
                                              all_e, l);
    }

    score_kernel<<<(BATCH * 64) / 256, 256, 0, stream>>>(all_e, users, pos_items, neg_items,
                                                         partials);
    reduce_finalize<<<1, 256, 0, stream>>>(partials, out);
}

// Round 6
// 521.507 us; speedup vs baseline: 2.5645x; 1.2487x over previous
//
#include <hip/hip_runtime.h>
#include <hip/hip_bf16.h>
#include <math.h>

#define U_CNT 50000
#define I_CNT 50000
#define N_CNT 100000
#define D 64
#define NNZ_CNT 3200000
#define LAYERS 3
#define BATCH 4096
#define L2_REG_F 1e-5f
#define EPS_F 1e-12f

#define NBUCKET 391     // 256 rows per bucket
#define SC_NBLK 320     // scatter blocks
#define SC_CHUNK 10000  // NNZ / SC_NBLK
#define BCNT_N (NBUCKET * SC_NBLK)       // 125,120
#define BCNT_NBLK ((BCNT_N + 255) / 256) // 489

typedef __attribute__((ext_vector_type(8))) short short8;
typedef __attribute__((ext_vector_type(4))) float floatx4;

__device__ __forceinline__ unsigned short f32_to_bf16(float f) {
    unsigned int u = __float_as_uint(f);
    u += 0x7FFFu + ((u >> 16) & 1u);   // round-to-nearest-even
    return (unsigned short)(u >> 16);
}
__device__ __forceinline__ float bf16_to_f32(unsigned short h) {
    return __uint_as_float(((unsigned int)h) << 16);
}

// ---------------- init: all_e[:,0:64] = concat(ue,ie) fp32; E_bf = bf16 copy
__global__ void init_E(const float* __restrict__ ue, const float* __restrict__ ie,
                       unsigned short* __restrict__ Ebf, float* __restrict__ all_e) {
    int tid = blockIdx.x * blockDim.x + threadIdx.x;
    if (tid >= N_CNT * D) return;
    int row = tid >> 6;
    int d = tid & 63;
    float v = (row < U_CNT) ? ue[tid] : ie[tid - U_CNT * D];
    Ebf[tid] = f32_to_bf16(v);
    all_e[(size_t)row * 256 + d] = v;
}

// ---------------- generic hierarchical exclusive scan (n <= 512*256)
__global__ void scan_p1(const int* __restrict__ in, int* __restrict__ bsums, int n) {
    __shared__ int s[256];
    int t = threadIdx.x;
    int i = blockIdx.x * 256 + t;
    int v = (i < n) ? in[i] : 0;
    s[t] = v;
    __syncthreads();
    for (int off = 128; off >= 1; off >>= 1) {
        if (t < off) s[t] += s[t + off];
        __syncthreads();
    }
    if (t == 0) bsums[blockIdx.x] = s[0];
}

__global__ void scan_p2(int* __restrict__ bsums, int nblk) {
    __shared__ int s[512];
    int t = threadIdx.x;
    int v = (t < nblk) ? bsums[t] : 0;
    s[t] = v;
    __syncthreads();
    for (int off = 1; off < 512; off <<= 1) {
        int x = (t >= off) ? s[t - off] : 0;
        __syncthreads();
        s[t] += x;
        __syncthreads();
    }
    if (t < nblk) bsums[t] = s[t] - v;  // exclusive
}

__global__ void scan_p3(const int* __restrict__ in, const int* __restrict__ bsums,
                        int* __restrict__ out, int n) {
    __shared__ int s[256];
    int t = threadIdx.x;
    int i = blockIdx.x * 256 + t;
    int v = (i < n) ? in[i] : 0;
    s[t] = v;
    __syncthreads();
    for (int off = 1; off < 256; off <<= 1) {
        int x = (t >= off) ? s[t - off] : 0;
        __syncthreads();
        s[t] += x;
        __syncthreads();
    }
    if (i < n) out[i] = s[t] - v + bsums[blockIdx.x];
}

// ---------------- per-block bucket histogram -> bcnt[bucket*SC_NBLK + blk]
__global__ __launch_bounds__(256) void bucket_hist(const int* __restrict__ rows,
                                                   int* __restrict__ bcnt) {
    __shared__ int h[NBUCKET];
    int blk = blockIdx.x, t = threadIdx.x;
    for (int b = t; b < NBUCKET; b += 256) h[b] = 0;
    __syncthreads();
    int s = blk * SC_CHUNK, e = s + SC_CHUNK;
    for (int i = s + t; i < e; i += 256) atomicAdd(&h[rows[i] >> 8], 1);
    __syncthreads();
    for (int b = t; b < NBUCKET; b += 256) bcnt[b * SC_NBLK + blk] = h[b];
}

// ---------------- scatter into per-(bucket,block) EXCLUSIVE regions (LDS cursors)
__global__ __launch_bounds__(256) void block_scatter(const int* __restrict__ rows,
                                                     const int* __restrict__ cols,
                                                     const float* __restrict__ vals,
                                                     const int* __restrict__ boff,
                                                     float2* __restrict__ bbuf) {
    __shared__ int cur[NBUCKET];
    int blk = blockIdx.x, t = threadIdx.x;
    for (int b = t; b < NBUCKET; b += 256) cur[b] = boff[b * SC_NBLK + blk];
    __syncthreads();
    int s = blk * SC_CHUNK, e = s + SC_CHUNK;
    for (int i = s + t; i < e; i += 256) {
        int r = rows[i];
        int b = r >> 8;
        int p = atomicAdd(&cur[b], 1);
        unsigned int bits = ((unsigned int)(r & 255) << 17) | (unsigned int)cols[i];
        bbuf[p] = make_float2(vals[i], __uint_as_float(bits));
    }
}

// ---------------- per-bucket: LDS rowlocal hist -> LDS scan -> row_ptr -> row-sorted packed
__global__ __launch_bounds__(256) void csr_finalize(const float2* __restrict__ bbuf,
                                                    const int* __restrict__ boff,
                                                    int* __restrict__ row_ptr,
                                                    float2* __restrict__ packed) {
    __shared__ int h[256];
    __shared__ int cur[256];
    int b = blockIdx.x, t = threadIdx.x;
    int s = boff[b * SC_NBLK];
    int e = (b == NBUCKET - 1) ? NNZ_CNT : boff[(b + 1) * SC_NBLK];
    h[t] = 0;
    __syncthreads();
    for (int i = s + t; i < e; i += 256)
        atomicAdd(&h[__float_as_uint(bbuf[i].y) >> 17], 1);
    __syncthreads();
    int v = h[t];
    for (int off = 1; off < 256; off <<= 1) {   // Hillis-Steele inclusive scan
        int x = (t >= off) ? h[t - off] : 0;
        __syncthreads();
        h[t] += x;
        __syncthreads();
    }
    int start = s + h[t] - v;  // exclusive + bucket base
    int row = (b << 8) + t;
    if (row < N_CNT) row_ptr[row] = start;
    cur[t] = start;
    if (b == 0 && t == 0) row_ptr[N_CNT] = NNZ_CNT;
    __syncthreads();
    for (int i = s + t; i < e; i += 256) {
        float2 rec = bbuf[i];
        unsigned int bits = __float_as_uint(rec.y);
        int p = atomicAdd(&cur[bits >> 17], 1);
        packed[p] = make_float2(rec.x, __int_as_float(bits & 0x1FFFFu));
    }
}

// ---------------- SpMM: one wave per row; 4 subgroups x 16 lanes, each subgroup
// handles one edge per iter (4 independent gathers in flight) + prefetched metadata.
__global__ __launch_bounds__(256) void spmm_bf16(const float2* __restrict__ packed,
                                                 const int* __restrict__ row_ptr,
                                                 const unsigned short* __restrict__ Ebf,
                                                 float* __restrict__ Lm) {
    int wid = (blockIdx.x * blockDim.x + threadIdx.x) >> 6;
    int lane = threadIdx.x & 63;
    if (wid >= N_CNT) return;
    int s = row_ptr[wid];
    int e = row_ptr[wid + 1];
    int sub = lane >> 4;   // edge slot within group of 4
    int sl = lane & 15;    // covers dims 4*sl .. 4*sl+3
    float ax = 0.f, ay = 0.f, az = 0.f, aw = 0.f;
    int i = s + sub;
    float2 rec = (i < e) ? packed[i] : make_float2(0.f, __int_as_float(0));
    while (i < e) {
        int inext = i + 4;
        float2 rnext = (inext < e) ? packed[inext] : make_float2(0.f, __int_as_float(0));
        int c = __float_as_int(rec.y);
        ushort4 ev = *(const ushort4*)(Ebf + (size_t)c * D + 4 * sl);
        float v = rec.x;
        ax += v * bf16_to_f32(ev.x);
        ay += v * bf16_to_f32(ev.y);
        az += v * bf16_to_f32(ev.z);
        aw += v * bf16_to_f32(ev.w);
        rec = rnext;
        i = inext;
    }
    ax += __shfl_xor(ax, 32, 64); ay += __shfl_xor(ay, 32, 64);
    az += __shfl_xor(az, 32, 64); aw += __shfl_xor(aw, 32, 64);
    ax += __shfl_xor(ax, 16, 64); ay += __shfl_xor(ay, 16, 64);
    az += __shfl_xor(az, 16, 64); aw += __shfl_xor(aw, 16, 64);
    if (sub == 0) {
        *(float4*)(Lm + (size_t)wid * D + 4 * sl) = make_float4(ax, ay, az, aw);
    }
}

// ---------------- fused layer via MFMA: Y = leaky([Lm+E | Lm*E] @ [W1;W2] + b1+b2)
// un-normalized Y -> Ebf (bf16), row-normalized Y -> all_e[:, (layer+1)*64:...]
// A tiles: 16 rows/wave, K=128, bf16, wave-private padded LDS. B: 16 register fragments.
#define AP 136  // A/B^T row stride in shorts (128 + 8 pad -> 4-bank stagger)
__global__ __launch_bounds__(256) void layer_fused_mfma(const float* __restrict__ Lm,
                                                        unsigned short* __restrict__ Ebf,
                                                        const float* __restrict__ W1,
                                                        const float* __restrict__ b1,
                                                        const float* __restrict__ W2,
                                                        const float* __restrict__ b2,
                                                        float* __restrict__ all_e, int layer) {
    __shared__ unsigned short sBt[64 * AP];    // B^T[n][k] bf16 (k<64: W1, k>=64: W2)
    __shared__ float sBias[64];
    __shared__ unsigned short sA[4][16 * AP];  // per-wave A staging

    int t = threadIdx.x;
    for (int i = t; i < 4096; i += 256) {
        int k = i >> 6, n = i & 63;
        sBt[n * AP + k] = f32_to_bf16(W1[i]);
        sBt[n * AP + 64 + k] = f32_to_bf16(W2[i]);
    }
    if (t < 64) sBias[t] = b1[t] + b2[t];
    __syncthreads();

    int w = t >> 6, lane = t & 63;
    int quad = lane >> 4, l16 = lane & 15;

    // B fragments: bfrag[ks][ct] = B[ks*32 + quad*8 + j][ct*16 + l16]
    short8 bfrag[4][4];
#pragma unroll
    for (int ks = 0; ks < 4; ks++)
#pragma unroll
        for (int ct = 0; ct < 4; ct++)
            bfrag[ks][ct] = *(const short8*)&sBt[(ct * 16 + l16) * AP + ks * 32 + quad * 8];

    float bias[4];
#pragma unroll
    for (int ct = 0; ct < 4; ct++) bias[ct] = sBias[ct * 16 + l16];

    unsigned short* A = sA[w];
    int col_off = (layer + 1) * 64;
    int nwaves = gridDim.x * 4;

    for (int tile = blockIdx.x * 4 + w; tile < N_CNT / 16; tile += nwaves) {
        int rbase = tile * 16;
        // stage A = [Lm+E | Lm*E] bf16 (wave-private; no block barrier needed)
#pragma unroll
        for (int p = 0; p < 4; p++) {
            int r = p * 4 + quad;
            int c = l16 * 4;
            float4 lv = *(const float4*)(Lm + (size_t)(rbase + r) * 64 + c);
            ushort4 eh = *(const ushort4*)(Ebf + (size_t)(rbase + r) * 64 + c);
            float e0 = bf16_to_f32(eh.x), e1 = bf16_to_f32(eh.y);
            float e2 = bf16_to_f32(eh.z), e3 = bf16_to_f32(eh.w);
            unsigned int x1a = f32_to_bf16(lv.x + e0) | ((unsigned int)f32_to_bf16(lv.y + e1) << 16);
            unsigned int x1b = f32_to_bf16(lv.z + e2) | ((unsigned int)f32_to_bf16(lv.w + e3) << 16);
            unsigned int x2a = f32_to_bf16(lv.x * e0) | ((unsigned int)f32_to_bf16(lv.y * e1) << 16);
            unsigned int x2b = f32_to_bf16(lv.z * e2) | ((unsigned int)f32_to_bf16(lv.w * e3) << 16);
            *(uint2*)&A[r * AP + c] = make_uint2(x1a, x1b);
            *(uint2*)&A[r * AP + 64 + c] = make_uint2(x2a, x2b);
        }
        // MFMA: acc init = bias (per-lane col fixed within a ct tile)
        floatx4 acc[4];
#pragma unroll
        for (int ct = 0; ct < 4; ct++) {
            acc[ct][0] = bias[ct]; acc[ct][1] = bias[ct];
            acc[ct][2] = bias[ct]; acc[ct][3] = bias[ct];
        }
#pragma unroll
        for (int ks = 0; ks < 4; ks++) {
            short8 af = *(const short8*)&A[l16 * AP + ks * 32 + quad * 8];
#pragma unroll
            for (int ct = 0; ct < 4; ct++)
                acc[ct] = __builtin_amdgcn_mfma_f32_16x16x32_bf16(af, bfrag[ks][ct], acc[ct], 0, 0, 0);
        }
        // epilogue: leaky relu; row-norm via 16-lane butterfly (row = quad*4+reg)
        float y[4][4];
        float ssq[4] = {0.f, 0.f, 0.f, 0.f};
#pragma unroll
        for (int ct = 0; ct < 4; ct++)
#pragma unroll
            for (int reg = 0; reg < 4; reg++) {
                float v = acc[ct][reg];
                v = (v > 0.f) ? v : 0.2f * v;
                y[ct][reg] = v;
                ssq[reg] += v * v;
            }
#pragma unroll
        for (int reg = 0; reg < 4; reg++) {
            float ss = ssq[reg];
            ss += __shfl_xor(ss, 1, 64);
            ss += __shfl_xor(ss, 2, 64);
            ss += __shfl_xor(ss, 4, 64);
            ss += __shfl_xor(ss, 8, 64);
            ssq[reg] = fmaxf(sqrtf(ss), EPS_F);
        }
#pragma unroll
        for (int reg = 0; reg < 4; reg++) {
            int row = rbase + quad * 4 + reg;
            float inv = 1.0f / ssq[reg];
#pragma unroll
            for (int ct = 0; ct < 4; ct++) {
                int col = ct * 16 + l16;
                float v = y[ct][reg];
                Ebf[(size_t)row * 64 + col] = f32_to_bf16(v);
                all_e[(size_t)row * 256 + col_off + col] = v * inv;
            }
        }
    }
}

// ---------------- scoring: one wave per sample, per-sample partials (NO atomics)
__device__ __forceinline__ float dot4(float4 a, float4 b) {
    return a.x * b.x + a.y * b.y + a.z * b.z + a.w * b.w;
}

__global__ __launch_bounds__(256) void score_kernel(const float* __restrict__ all_e,
                                                    const int* __restrict__ users,
                                                    const int* __restrict__ pos,
                                                    const int* __restrict__ neg,
                                                    float4* __restrict__ partials) {
    int wid = (blockIdx.x * blockDim.x + threadIdx.x) >> 6;
    int lane = threadIdx.x & 63;
    if (wid >= BATCH) return;
    int ui = users[wid];
    int pi = pos[wid];
    int ni = neg[wid];
    const float4* uv4 = (const float4*)(all_e + (size_t)ui * 256);
    const float4* pv4 = (const float4*)(all_e + (size_t)pi * 256);
    const float4* nv4 = (const float4*)(all_e + (size_t)ni * 256);
    float4 uv = uv4[lane];
    float4 pv = pv4[lane];
    float4 nv = nv4[lane];
    float s_up = dot4(uv, pv);
    float s_un = dot4(uv, nv);
    float s_uu = dot4(uv, uv);
    float s_pp = dot4(pv, pv);
    float s_nn = dot4(nv, nv);
#pragma unroll
    for (int off = 32; off >= 1; off >>= 1) {
        s_up += __shfl_xor(s_up, off, 64);
        s_un += __shfl_xor(s_un, off, 64);
        s_uu += __shfl_xor(s_uu, off, 64);
        s_pp += __shfl_xor(s_pp, off, 64);
        s_nn += __shfl_xor(s_nn, off, 64);
    }
    if (lane == 0) {
        float x = s_up - s_un;
        float ls = fminf(x, 0.f) - log1pf(expf(-fabsf(x)));  // log_sigmoid
        partials[wid] = make_float4(-ls, s_uu, s_pp, s_nn);
    }
}

// single-block tree reduction over 4096 float4 partials + final scalar
__global__ __launch_bounds__(256) void reduce_finalize(const float4* __restrict__ partials,
                                                       float* __restrict__ out) {
    __shared__ float4 s[256];
    int t = threadIdx.x;
    float4 a = make_float4(0.f, 0.f, 0.f, 0.f);
    for (int i = t; i < BATCH; i += 256) {
        float4 p = partials[i];
        a.x += p.x; a.y += p.y; a.z += p.z; a.w += p.w;
    }
    s[t] = a;
    __syncthreads();
    for (int off = 128; off >= 1; off >>= 1) {
        if (t < off) {
            s[t].x += s[t + off].x;
            s[t].y += s[t + off].y;
            s[t].z += s[t + off].z;
            s[t].w += s[t + off].w;
        }
        __syncthreads();
    }
    if (t == 0) {
        float bpr = s[0].x / (float)BATCH;
        float l2norm = (s[0].y + s[0].z + sqrtf(s[0].w)) * 0.5f;
        out[0] = bpr + L2_REG_F * l2norm / (float)BATCH;
    }
}

extern "C" void kernel_launch(void* const* d_in, const int* in_sizes, int n_in,
                              void* d_out, int out_size, void* d_ws, size_t ws_size,
                              hipStream_t stream) {
    const int* users = (const int*)d_in[0];
    const int* pos_items = (const int*)d_in[1];
    const int* neg_items = (const int*)d_in[2];
    const int* rows = (const int*)d_in[3];
    const int* cols = (const int*)d_in[4];
    const float* vals = (const float*)d_in[5];
    const float* user_embed = (const float*)d_in[6];
    const float* item_embed = (const float*)d_in[7];
    const float* W1 = (const float*)d_in[8];
    const float* b1 = (const float*)d_in[9];
    const float* W2 = (const float*)d_in[10];
    const float* b2 = (const float*)d_in[11];
    float* out = (float*)d_out;

    char* ws = (char*)d_ws;
    size_t off_alle = 0;                                     // 102,400,000
    size_t off_Lm = off_alle + (size_t)N_CNT * 256 * 4;      // 25,600,000
    size_t off_packed = off_Lm + (size_t)N_CNT * D * 4;      // 25,600,000
    size_t off_Ebf = off_packed + (size_t)NNZ_CNT * 8;       // 12,800,000
    size_t off_rowptr = off_Ebf + (size_t)N_CNT * D * 2;     // 400,128
    size_t off_blkB = off_rowptr + 400128;                   // 2,048 (489 block sums)
    size_t off_bcnt = off_blkB + 2048;                       // 500,480 (391*320 ints)
    size_t off_part = off_bcnt + 500480;                     // 65,536

    float* all_e = (float*)(ws + off_alle);
    float2* bbuf = (float2*)(ws + off_alle);   // aliases all_e; dead before init_E runs
    float* Lm = (float*)(ws + off_Lm);
    float2* packed = (float2*)(ws + off_packed);
    unsigned short* Ebf = (unsigned short*)(ws + off_Ebf);
    int* row_ptr = (int*)(ws + off_rowptr);
    int* blkB = (int*)(ws + off_blkB);
    int* bcnt = (int*)(ws + off_bcnt);
    float4* partials = (float4*)(ws + off_part);

    // bucketed multisplit with exclusive per-(bucket,block) regions
    bucket_hist<<<SC_NBLK, 256, 0, stream>>>(rows, bcnt);
    scan_p1<<<BCNT_NBLK, 256, 0, stream>>>(bcnt, blkB, BCNT_N);
    scan_p2<<<1, 512, 0, stream>>>(blkB, BCNT_NBLK);
    scan_p3<<<BCNT_NBLK, 256, 0, stream>>>(bcnt, blkB, bcnt, BCNT_N);  // in-place
    block_scatter<<<SC_NBLK, 256, 0, stream>>>(rows, cols, vals, bcnt, bbuf);
    csr_finalize<<<NBUCKET, 256, 0, stream>>>(bbuf, bcnt, row_ptr, packed);

    // embeddings (after csr_finalize: bbuf aliases all_e)
    init_E<<<(N_CNT * D) / 256, 256, 0, stream>>>(user_embed, item_embed, Ebf, all_e);

    for (int l = 0; l < LAYERS; l++) {
        spmm_bf16<<<(N_CNT * 64) / 256, 256, 0, stream>>>(packed, row_ptr, Ebf, Lm);
        layer_fused_mfma<<<784, 256, 0, stream>>>(Lm, Ebf, W1 + (size_t)l * 4096,
                                                  b1 + (size_t)l * 64, W2 + (size_t)l * 4096,
                                                  b2 + (size_t)l * 64, all_e, l);
    }

    score_kernel<<<(BATCH * 64) / 256, 256, 0, stream>>>(all_e, users, pos_items, neg_items,
                                                         partials);
    reduce_finalize<<<1, 256, 0, stream>>>(partials, out);
}

// Round 7
// 484.375 us; speedup vs baseline: 2.7611x; 1.0767x over previous
//
#include <hip/hip_runtime.h>
#include <hip/hip_bf16.h>
#include <math.h>

#define U_CNT 50000
#define I_CNT 50000
#define N_CNT 100000
#define D 64
#define NNZ_CNT 3200000
#define LAYERS 3
#define BATCH 4096
#define L2_REG_F 1e-5f
#define EPS_F 1e-12f

#define NBUCKET 391     // 256 rows per bucket
#define SC_NBLK 320     // scatter blocks
#define SC_CHUNK 10000  // NNZ / SC_NBLK
#define BCNT_N (NBUCKET * SC_NBLK)       // 125,120
#define BCNT_NBLK ((BCNT_N + 255) / 256) // 489

typedef __attribute__((ext_vector_type(8))) short short8;
typedef __attribute__((ext_vector_type(4))) float floatx4;

__device__ __forceinline__ unsigned short f32_to_bf16(float f) {
    unsigned int u = __float_as_uint(f);
    u += 0x7FFFu + ((u >> 16) & 1u);   // round-to-nearest-even
    return (unsigned short)(u >> 16);
}
__device__ __forceinline__ float bf16_to_f32(unsigned short h) {
    return __uint_as_float(((unsigned int)h) << 16);
}
__device__ __forceinline__ float bf16_lo(unsigned int u) {
    return __uint_as_float(u << 16);
}
__device__ __forceinline__ float bf16_hi(unsigned int u) {
    return __uint_as_float(u & 0xFFFF0000u);
}

// ---------------- init: all_e[:,0:64] = concat(ue,ie) fp32; E_bf = bf16 copy
__global__ void init_E(const float* __restrict__ ue, const float* __restrict__ ie,
                       unsigned short* __restrict__ Ebf, float* __restrict__ all_e) {
    int tid = blockIdx.x * blockDim.x + threadIdx.x;
    if (tid >= N_CNT * D) return;
    int row = tid >> 6;
    int d = tid & 63;
    float v = (row < U_CNT) ? ue[tid] : ie[tid - U_CNT * D];
    Ebf[tid] = f32_to_bf16(v);
    all_e[(size_t)row * 256 + d] = v;
}

// ---------------- generic hierarchical exclusive scan (n <= 512*256)
__global__ void scan_p1(const int* __restrict__ in, int* __restrict__ bsums, int n) {
    __shared__ int s[256];
    int t = threadIdx.x;
    int i = blockIdx.x * 256 + t;
    int v = (i < n) ? in[i] : 0;
    s[t] = v;
    __syncthreads();
    for (int off = 128; off >= 1; off >>= 1) {
        if (t < off) s[t] += s[t + off];
        __syncthreads();
    }
    if (t == 0) bsums[blockIdx.x] = s[0];
}

__global__ void scan_p2(int* __restrict__ bsums, int nblk) {
    __shared__ int s[512];
    int t = threadIdx.x;
    int v = (t < nblk) ? bsums[t] : 0;
    s[t] = v;
    __syncthreads();
    for (int off = 1; off < 512; off <<= 1) {
        int x = (t >= off) ? s[t - off] : 0;
        __syncthreads();
        s[t] += x;
        __syncthreads();
    }
    if (t < nblk) bsums[t] = s[t] - v;  // exclusive
}

__global__ void scan_p3(const int* __restrict__ in, const int* __restrict__ bsums,
                        int* __restrict__ out, int n) {
    __shared__ int s[256];
    int t = threadIdx.x;
    int i = blockIdx.x * 256 + t;
    int v = (i < n) ? in[i] : 0;
    s[t] = v;
    __syncthreads();
    for (int off = 1; off < 256; off <<= 1) {
        int x = (t >= off) ? s[t - off] : 0;
        __syncthreads();
        s[t] += x;
        __syncthreads();
    }
    if (i < n) out[i] = s[t] - v + bsums[blockIdx.x];
}

// ---------------- per-block bucket histogram -> bcnt[bucket*SC_NBLK + blk]
__global__ __launch_bounds__(256) void bucket_hist(const int* __restrict__ rows,
                                                   int* __restrict__ bcnt) {
    __shared__ int h[NBUCKET];
    int blk = blockIdx.x, t = threadIdx.x;
    for (int b = t; b < NBUCKET; b += 256) h[b] = 0;
    __syncthreads();
    int s = blk * SC_CHUNK, e = s + SC_CHUNK;
    for (int i = s + t; i < e; i += 256) atomicAdd(&h[rows[i] >> 8], 1);
    __syncthreads();
    for (int b = t; b < NBUCKET; b += 256) bcnt[b * SC_NBLK + blk] = h[b];
}

// ---------------- scatter into per-(bucket,block) EXCLUSIVE regions (LDS cursors)
__global__ __launch_bounds__(256) void block_scatter(const int* __restrict__ rows,
                                                     const int* __restrict__ cols,
                                                     const float* __restrict__ vals,
                                                     const int* __restrict__ boff,
                                                     float2* __restrict__ bbuf) {
    __shared__ int cur[NBUCKET];
    int blk = blockIdx.x, t = threadIdx.x;
    for (int b = t; b < NBUCKET; b += 256) cur[b] = boff[b * SC_NBLK + blk];
    __syncthreads();
    int s = blk * SC_CHUNK, e = s + SC_CHUNK;
    for (int i = s + t; i < e; i += 256) {
        int r = rows[i];
        int b = r >> 8;
        int p = atomicAdd(&cur[b], 1);
        unsigned int bits = ((unsigned int)(r & 255) << 17) | (unsigned int)cols[i];
        bbuf[p] = make_float2(vals[i], __uint_as_float(bits));
    }
}

// ---------------- per-bucket: LDS rowlocal hist -> LDS scan -> row_ptr -> row-sorted packed
__global__ __launch_bounds__(256) void csr_finalize(const float2* __restrict__ bbuf,
                                                    const int* __restrict__ boff,
                                                    int* __restrict__ row_ptr,
                                                    float2* __restrict__ packed) {
    __shared__ int h[256];
    __shared__ int cur[256];
    int b = blockIdx.x, t = threadIdx.x;
    int s = boff[b * SC_NBLK];
    int e = (b == NBUCKET - 1) ? NNZ_CNT : boff[(b + 1) * SC_NBLK];
    h[t] = 0;
    __syncthreads();
    for (int i = s + t; i < e; i += 256)
        atomicAdd(&h[__float_as_uint(bbuf[i].y) >> 17], 1);
    __syncthreads();
    int v = h[t];
    for (int off = 1; off < 256; off <<= 1) {   // Hillis-Steele inclusive scan
        int x = (t >= off) ? h[t - off] : 0;
        __syncthreads();
        h[t] += x;
        __syncthreads();
    }
    int start = s + h[t] - v;  // exclusive + bucket base
    int row = (b << 8) + t;
    if (row < N_CNT) row_ptr[row] = start;
    cur[t] = start;
    if (b == 0 && t == 0) row_ptr[N_CNT] = NNZ_CNT;
    __syncthreads();
    for (int i = s + t; i < e; i += 256) {
        float2 rec = bbuf[i];
        unsigned int bits = __float_as_uint(rec.y);
        int p = atomicAdd(&cur[bits >> 17], 1);
        packed[p] = make_float2(rec.x, __int_as_float(bits & 0x1FFFFu));
    }
}

// ---------------- SpMM: one wave per row; 8 subgroups x 8 lanes. Each subgroup
// gathers one edge's E-row slice per iter -> 8 independent 128B gathers in flight
// per wave; lane covers 8 dims via one 16B load. Metadata prefetched one step ahead.
__global__ __launch_bounds__(256) void spmm_bf16(const float2* __restrict__ packed,
                                                 const int* __restrict__ row_ptr,
                                                 const unsigned short* __restrict__ Ebf,
                                                 float* __restrict__ Lm) {
    int wid = (blockIdx.x * blockDim.x + threadIdx.x) >> 6;
    int lane = threadIdx.x & 63;
    if (wid >= N_CNT) return;
    int s = row_ptr[wid];
    int e = row_ptr[wid + 1];
    int sub = lane >> 3;   // edge slot within group of 8
    int sl = lane & 7;     // covers dims 8*sl .. 8*sl+7
    float a0 = 0.f, a1 = 0.f, a2 = 0.f, a3 = 0.f;
    float a4 = 0.f, a5 = 0.f, a6 = 0.f, a7 = 0.f;
    int i = s + sub;
    float2 rec = (i < e) ? packed[i] : make_float2(0.f, __int_as_float(0));
    while (i < e) {
        int inext = i + 8;
        float2 rnext = (inext < e) ? packed[inext] : make_float2(0.f, __int_as_float(0));
        int c = __float_as_int(rec.y);
        uint4 ev = *(const uint4*)(Ebf + (size_t)c * D + 8 * sl);
        float v = rec.x;
        a0 += v * bf16_lo(ev.x); a1 += v * bf16_hi(ev.x);
        a2 += v * bf16_lo(ev.y); a3 += v * bf16_hi(ev.y);
        a4 += v * bf16_lo(ev.z); a5 += v * bf16_hi(ev.z);
        a6 += v * bf16_lo(ev.w); a7 += v * bf16_hi(ev.w);
        rec = rnext;
        i = inext;
    }
    // sum the 8 edge-slot partials (lanes sl, sl+8, ..., sl+56)
#pragma unroll
    for (int off = 32; off >= 8; off >>= 1) {
        a0 += __shfl_xor(a0, off, 64); a1 += __shfl_xor(a1, off, 64);
        a2 += __shfl_xor(a2, off, 64); a3 += __shfl_xor(a3, off, 64);
        a4 += __shfl_xor(a4, off, 64); a5 += __shfl_xor(a5, off, 64);
        a6 += __shfl_xor(a6, off, 64); a7 += __shfl_xor(a7, off, 64);
    }
    if (sub == 0) {
        float* dst = Lm + (size_t)wid * D + 8 * sl;
        *(float4*)dst = make_float4(a0, a1, a2, a3);
        *(float4*)(dst + 4) = make_float4(a4, a5, a6, a7);
    }
}

// ---------------- fused layer via MFMA: Y = leaky([Lm+E | Lm*E] @ [W1;W2] + b1+b2)
// un-normalized Y -> Ebf (bf16), row-normalized Y -> all_e[:, (layer+1)*64:...]
#define AP 136  // A/B^T row stride in shorts (128 + 8 pad -> 4-bank stagger)
__global__ __launch_bounds__(256) void layer_fused_mfma(const float* __restrict__ Lm,
                                                        unsigned short* __restrict__ Ebf,
                                                        const float* __restrict__ W1,
                                                        const float* __restrict__ b1,
                                                        const float* __restrict__ W2,
                                                        const float* __restrict__ b2,
                                                        float* __restrict__ all_e, int layer) {
    __shared__ unsigned short sBt[64 * AP];    // B^T[n][k] bf16 (k<64: W1, k>=64: W2)
    __shared__ float sBias[64];
    __shared__ unsigned short sA[4][16 * AP];  // per-wave A staging

    int t = threadIdx.x;
    for (int i = t; i < 4096; i += 256) {
        int k = i >> 6, n = i & 63;
        sBt[n * AP + k] = f32_to_bf16(W1[i]);
        sBt[n * AP + 64 + k] = f32_to_bf16(W2[i]);
    }
    if (t < 64) sBias[t] = b1[t] + b2[t];
    __syncthreads();

    int w = t >> 6, lane = t & 63;
    int quad = lane >> 4, l16 = lane & 15;

    short8 bfrag[4][4];
#pragma unroll
    for (int ks = 0; ks < 4; ks++)
#pragma unroll
        for (int ct = 0; ct < 4; ct++)
            bfrag[ks][ct] = *(const short8*)&sBt[(ct * 16 + l16) * AP + ks * 32 + quad * 8];

    float bias[4];
#pragma unroll
    for (int ct = 0; ct < 4; ct++) bias[ct] = sBias[ct * 16 + l16];

    unsigned short* A = sA[w];
    int col_off = (layer + 1) * 64;
    int nwaves = gridDim.x * 4;

    for (int tile = blockIdx.x * 4 + w; tile < N_CNT / 16; tile += nwaves) {
        int rbase = tile * 16;
#pragma unroll
        for (int p = 0; p < 4; p++) {
            int r = p * 4 + quad;
            int c = l16 * 4;
            float4 lv = *(const float4*)(Lm + (size_t)(rbase + r) * 64 + c);
            ushort4 eh = *(const ushort4*)(Ebf + (size_t)(rbase + r) * 64 + c);
            float e0 = bf16_to_f32(eh.x), e1 = bf16_to_f32(eh.y);
            float e2 = bf16_to_f32(eh.z), e3 = bf16_to_f32(eh.w);
            unsigned int x1a = f32_to_bf16(lv.x + e0) | ((unsigned int)f32_to_bf16(lv.y + e1) << 16);
            unsigned int x1b = f32_to_bf16(lv.z + e2) | ((unsigned int)f32_to_bf16(lv.w + e3) << 16);
            unsigned int x2a = f32_to_bf16(lv.x * e0) | ((unsigned int)f32_to_bf16(lv.y * e1) << 16);
            unsigned int x2b = f32_to_bf16(lv.z * e2) | ((unsigned int)f32_to_bf16(lv.w * e3) << 16);
            *(uint2*)&A[r * AP + c] = make_uint2(x1a, x1b);
            *(uint2*)&A[r * AP + 64 + c] = make_uint2(x2a, x2b);
        }
        floatx4 acc[4];
#pragma unroll
        for (int ct = 0; ct < 4; ct++) {
            acc[ct][0] = bias[ct]; acc[ct][1] = bias[ct];
            acc[ct][2] = bias[ct]; acc[ct][3] = bias[ct];
        }
#pragma unroll
        for (int ks = 0; ks < 4; ks++) {
            short8 af = *(const short8*)&A[l16 * AP + ks * 32 + quad * 8];
#pragma unroll
            for (int ct = 0; ct < 4; ct++)
                acc[ct] = __builtin_amdgcn_mfma_f32_16x16x32_bf16(af, bfrag[ks][ct], acc[ct], 0, 0, 0);
        }
        float y[4][4];
        float ssq[4] = {0.f, 0.f, 0.f, 0.f};
#pragma unroll
        for (int ct = 0; ct < 4; ct++)
#pragma unroll
            for (int reg = 0; reg < 4; reg++) {
                float v = acc[ct][reg];
                v = (v > 0.f) ? v : 0.2f * v;
                y[ct][reg] = v;
                ssq[reg] += v * v;
            }
#pragma unroll
        for (int reg = 0; reg < 4; reg++) {
            float ss = ssq[reg];
            ss += __shfl_xor(ss, 1, 64);
            ss += __shfl_xor(ss, 2, 64);
            ss += __shfl_xor(ss, 4, 64);
            ss += __shfl_xor(ss, 8, 64);
            ssq[reg] = fmaxf(sqrtf(ss), EPS_F);
        }
#pragma unroll
        for (int reg = 0; reg < 4; reg++) {
            int row = rbase + quad * 4 + reg;
            float inv = 1.0f / ssq[reg];
#pragma unroll
            for (int ct = 0; ct < 4; ct++) {
                int col = ct * 16 + l16;
                float v = y[ct][reg];
                Ebf[(size_t)row * 64 + col] = f32_to_bf16(v);
                all_e[(size_t)row * 256 + col_off + col] = v * inv;
            }
        }
    }
}

// ---------------- scoring: one wave per sample, per-sample partials (NO atomics)
__device__ __forceinline__ float dot4(float4 a, float4 b) {
    return a.x * b.x + a.y * b.y + a.z * b.z + a.w * b.w;
}

__global__ __launch_bounds__(256) void score_kernel(const float* __restrict__ all_e,
                                                    const int* __restrict__ users,
                                                    const int* __restrict__ pos,
                                                    const int* __restrict__ neg,
                                                    float4* __restrict__ partials) {
    int wid = (blockIdx.x * blockDim.x + threadIdx.x) >> 6;
    int lane = threadIdx.x & 63;
    if (wid >= BATCH) return;
    int ui = users[wid];
    int pi = pos[wid];
    int ni = neg[wid];
    const float4* uv4 = (const float4*)(all_e + (size_t)ui * 256);
    const float4* pv4 = (const float4*)(all_e + (size_t)pi * 256);
    const float4* nv4 = (const float4*)(all_e + (size_t)ni * 256);
    float4 uv = uv4[lane];
    float4 pv = pv4[lane];
    float4 nv = nv4[lane];
    float s_up = dot4(uv, pv);
    float s_un = dot4(uv, nv);
    float s_uu = dot4(uv, uv);
    float s_pp = dot4(pv, pv);
    float s_nn = dot4(nv, nv);
#pragma unroll
    for (int off = 32; off >= 1; off >>= 1) {
        s_up += __shfl_xor(s_up, off, 64);
        s_un += __shfl_xor(s_un, off, 64);
        s_uu += __shfl_xor(s_uu, off, 64);
        s_pp += __shfl_xor(s_pp, off, 64);
        s_nn += __shfl_xor(s_nn, off, 64);
    }
    if (lane == 0) {
        float x = s_up - s_un;
        float ls = fminf(x, 0.f) - log1pf(expf(-fabsf(x)));  // log_sigmoid
        partials[wid] = make_float4(-ls, s_uu, s_pp, s_nn);
    }
}

// single-block tree reduction over 4096 float4 partials + final scalar
__global__ __launch_bounds__(256) void reduce_finalize(const float4* __restrict__ partials,
                                                       float* __restrict__ out) {
    __shared__ float4 s[256];
    int t = threadIdx.x;
    float4 a = make_float4(0.f, 0.f, 0.f, 0.f);
    for (int i = t; i < BATCH; i += 256) {
        float4 p = partials[i];
        a.x += p.x; a.y += p.y; a.z += p.z; a.w += p.w;
    }
    s[t] = a;
    __syncthreads();
    for (int off = 128; off >= 1; off >>= 1) {
        if (t < off) {
            s[t].x += s[t + off].x;
            s[t].y += s[t + off].y;
            s[t].z += s[t + off].z;
            s[t].w += s[t + off].w;
        }
        __syncthreads();
    }
    if (t == 0) {
        float bpr = s[0].x / (float)BATCH;
        float l2norm = (s[0].y + s[0].z + sqrtf(s[0].w)) * 0.5f;
        out[0] = bpr + L2_REG_F * l2norm / (float)BATCH;
    }
}

extern "C" void kernel_launch(void* const* d_in, const int* in_sizes, int n_in,
                              void* d_out, int out_size, void* d_ws, size_t ws_size,
                              hipStream_t stream) {
    const int* users = (const int*)d_in[0];
    const int* pos_items = (const int*)d_in[1];
    const int* neg_items = (const int*)d_in[2];
    const int* rows = (const int*)d_in[3];
    const int* cols = (const int*)d_in[4];
    const float* vals = (const float*)d_in[5];
    const float* user_embed = (const float*)d_in[6];
    const float* item_embed = (const float*)d_in[7];
    const float* W1 = (const float*)d_in[8];
    const float* b1 = (const float*)d_in[9];
    const float* W2 = (const float*)d_in[10];
    const float* b2 = (const float*)d_in[11];
    float* out = (float*)d_out;

    char* ws = (char*)d_ws;
    size_t off_alle = 0;                                     // 102,400,000
    size_t off_Lm = off_alle + (size_t)N_CNT * 256 * 4;      // 25,600,000
    size_t off_packed = off_Lm + (size_t)N_CNT * D * 4;      // 25,600,000
    size_t off_Ebf = off_packed + (size_t)NNZ_CNT * 8;       // 12,800,000
    size_t off_rowptr = off_Ebf + (size_t)N_CNT * D * 2;     // 400,128
    size_t off_blkB = off_rowptr + 400128;                   // 2,048 (489 block sums)
    size_t off_bcnt = off_blkB + 2048;                       // 500,480 (391*320 ints)
    size_t off_part = off_bcnt + 500480;                     // 65,536

    float* all_e = (float*)(ws + off_alle);
    float2* bbuf = (float2*)(ws + off_alle);   // aliases all_e; dead before init_E runs
    float* Lm = (float*)(ws + off_Lm);
    float2* packed = (float2*)(ws + off_packed);
    unsigned short* Ebf = (unsigned short*)(ws + off_Ebf);
    int* row_ptr = (int*)(ws + off_rowptr);
    int* blkB = (int*)(ws + off_blkB);
    int* bcnt = (int*)(ws + off_bcnt);
    float4* partials = (float4*)(ws + off_part);

    // bucketed multisplit with exclusive per-(bucket,block) regions
    bucket_hist<<<SC_NBLK, 256, 0, stream>>>(rows, bcnt);
    scan_p1<<<BCNT_NBLK, 256, 0, stream>>>(bcnt, blkB, BCNT_N);
    scan_p2<<<1, 512, 0, stream>>>(blkB, BCNT_NBLK);
    scan_p3<<<BCNT_NBLK, 256, 0, stream>>>(bcnt, blkB, bcnt, BCNT_N);  // in-place
    block_scatter<<<SC_NBLK, 256, 0, stream>>>(rows, cols, vals, bcnt, bbuf);
    csr_finalize<<<NBUCKET, 256, 0, stream>>>(bbuf, bcnt, row_ptr, packed);

    // embeddings (after csr_finalize: bbuf aliases all_e)
    init_E<<<(N_CNT * D) / 256, 256, 0, stream>>>(user_embed, item_embed, Ebf, all_e);

    for (int l = 0; l < LAYERS; l++) {
        spmm_bf16<<<(N_CNT * 64) / 256, 256, 0, stream>>>(packed, row_ptr, Ebf, Lm);
        layer_fused_mfma<<<784, 256, 0, stream>>>(Lm, Ebf, W1 + (size_t)l * 4096,
                                                  b1 + (size_t)l * 64, W2 + (size_t)l * 4096,
                                                  b2 + (size_t)l * 64, all_e, l);
    }

    score_kernel<<<(BATCH * 64) / 256, 256, 0, stream>>>(all_e, users, pos_items, neg_items,
                                                         partials);
    reduce_finalize<<<1, 256, 0, stream>>>(partials, out);
}

// Round 8
// 442.060 us; speedup vs baseline: 3.0254x; 1.0957x over previous
//
#include <hip/hip_runtime.h>
#include <hip/hip_bf16.h>
#include <math.h>

#define U_CNT 50000
#define I_CNT 50000
#define N_CNT 100000
#define D 64
#define NNZ_CNT 3200000
#define LAYERS 3
#define BATCH 4096
#define L2_REG_F 1e-5f
#define EPS_F 1e-12f

#define NBUCKET 391     // 256 rows per bucket
#define SC_NBLK 256     // scatter blocks (1 per CU), 1024 threads each
#define SC_CHUNK 12500  // NNZ / SC_NBLK
#define BCNT_N (NBUCKET * SC_NBLK)       // 100,096
#define BCNT_NBLK ((BCNT_N + 255) / 256) // 392

typedef __attribute__((ext_vector_type(8))) short short8;
typedef __attribute__((ext_vector_type(4))) float floatx4;

__device__ __forceinline__ unsigned short f32_to_bf16(float f) {
    unsigned int u = __float_as_uint(f);
    u += 0x7FFFu + ((u >> 16) & 1u);   // round-to-nearest-even
    return (unsigned short)(u >> 16);
}
__device__ __forceinline__ float bf16_to_f32(unsigned short h) {
    return __uint_as_float(((unsigned int)h) << 16);
}
__device__ __forceinline__ float bf16_lo(unsigned int u) {
    return __uint_as_float(u << 16);
}
__device__ __forceinline__ float bf16_hi(unsigned int u) {
    return __uint_as_float(u & 0xFFFF0000u);
}

// ---------------- init: all_e[:,0:64] = concat(ue,ie) fp32; E_bf = bf16 copy
__global__ void init_E(const float* __restrict__ ue, const float* __restrict__ ie,
                       unsigned short* __restrict__ Ebf, float* __restrict__ all_e) {
    int tid = blockIdx.x * blockDim.x + threadIdx.x;
    if (tid >= N_CNT * D) return;
    int row = tid >> 6;
    int d = tid & 63;
    float v = (row < U_CNT) ? ue[tid] : ie[tid - U_CNT * D];
    Ebf[tid] = f32_to_bf16(v);
    all_e[(size_t)row * 256 + d] = v;
}

// ---------------- generic hierarchical exclusive scan (n <= 512*256)
__global__ void scan_p1(const int* __restrict__ in, int* __restrict__ bsums, int n) {
    __shared__ int s[256];
    int t = threadIdx.x;
    int i = blockIdx.x * 256 + t;
    int v = (i < n) ? in[i] : 0;
    s[t] = v;
    __syncthreads();
    for (int off = 128; off >= 1; off >>= 1) {
        if (t < off) s[t] += s[t + off];
        __syncthreads();
    }
    if (t == 0) bsums[blockIdx.x] = s[0];
}

__global__ void scan_p2(int* __restrict__ bsums, int nblk) {
    __shared__ int s[512];
    int t = threadIdx.x;
    int v = (t < nblk) ? bsums[t] : 0;
    s[t] = v;
    __syncthreads();
    for (int off = 1; off < 512; off <<= 1) {
        int x = (t >= off) ? s[t - off] : 0;
        __syncthreads();
        s[t] += x;
        __syncthreads();
    }
    if (t < nblk) bsums[t] = s[t] - v;  // exclusive
}

__global__ void scan_p3(const int* __restrict__ in, const int* __restrict__ bsums,
                        int* __restrict__ out, int n) {
    __shared__ int s[256];
    int t = threadIdx.x;
    int i = blockIdx.x * 256 + t;
    int v = (i < n) ? in[i] : 0;
    s[t] = v;
    __syncthreads();
    for (int off = 1; off < 256; off <<= 1) {
        int x = (t >= off) ? s[t - off] : 0;
        __syncthreads();
        s[t] += x;
        __syncthreads();
    }
    if (i < n) out[i] = s[t] - v + bsums[blockIdx.x];
}

// ---------------- per-block bucket histogram -> bcnt[bucket*SC_NBLK + blk]
__global__ __launch_bounds__(1024) void bucket_hist(const int* __restrict__ rows,
                                                    int* __restrict__ bcnt) {
    __shared__ int h[NBUCKET];
    int blk = blockIdx.x, t = threadIdx.x;
    if (t < NBUCKET) h[t] = 0;
    __syncthreads();
    int s = blk * SC_CHUNK, e = s + SC_CHUNK;
    for (int i = s + t; i < e; i += 1024) atomicAdd(&h[rows[i] >> 8], 1);
    __syncthreads();
    if (t < NBUCKET) bcnt[t * SC_NBLK + blk] = h[t];
}

// ---------------- scatter into per-(bucket,block) EXCLUSIVE regions (LDS cursors)
__global__ __launch_bounds__(1024) void block_scatter(const int* __restrict__ rows,
                                                      const int* __restrict__ cols,
                                                      const float* __restrict__ vals,
                                                      const int* __restrict__ boff,
                                                      float2* __restrict__ bbuf) {
    __shared__ int cur[NBUCKET];
    int blk = blockIdx.x, t = threadIdx.x;
    if (t < NBUCKET) cur[t] = boff[t * SC_NBLK + blk];
    __syncthreads();
    int s = blk * SC_CHUNK, e = s + SC_CHUNK;
    for (int i = s + t; i < e; i += 1024) {
        int r = rows[i];
        int b = r >> 8;
        int p = atomicAdd(&cur[b], 1);
        unsigned int bits = ((unsigned int)(r & 255) << 17) | (unsigned int)cols[i];
        bbuf[p] = make_float2(vals[i], __uint_as_float(bits));
    }
}

// ---------------- per-bucket: LDS rowlocal hist -> LDS scan -> row_ptr -> row-sorted packed
__global__ __launch_bounds__(1024) void csr_finalize(const float2* __restrict__ bbuf,
                                                     const int* __restrict__ boff,
                                                     int* __restrict__ row_ptr,
                                                     float2* __restrict__ packed) {
    __shared__ int h[256];
    __shared__ int cur[256];
    int b = blockIdx.x, t = threadIdx.x;
    int s = boff[b * SC_NBLK];
    int e = (b == NBUCKET - 1) ? NNZ_CNT : boff[(b + 1) * SC_NBLK];
    if (t < 256) h[t] = 0;
    __syncthreads();
    for (int i = s + t; i < e; i += 1024)
        atomicAdd(&h[__float_as_uint(bbuf[i].y) >> 17], 1);
    __syncthreads();
    int v = (t < 256) ? h[t] : 0;
    for (int off = 1; off < 256; off <<= 1) {   // Hillis-Steele inclusive scan (t<256)
        int x = (t >= off && t < 256) ? h[t - off] : 0;
        __syncthreads();
        if (t < 256) h[t] += x;
        __syncthreads();
    }
    if (t < 256) {
        int start = s + h[t] - v;  // exclusive + bucket base
        int row = (b << 8) + t;
        if (row < N_CNT) row_ptr[row] = start;
        cur[t] = start;
        if (b == 0 && t == 0) row_ptr[N_CNT] = NNZ_CNT;
    }
    __syncthreads();
    for (int i = s + t; i < e; i += 1024) {
        float2 rec = bbuf[i];
        unsigned int bits = __float_as_uint(rec.y);
        int p = atomicAdd(&cur[bits >> 17], 1);
        packed[p] = make_float2(rec.x, __int_as_float(bits & 0x1FFFFu));
    }
}

// ---------------- SpMM: one wave per row; 8 subgroups x 8 lanes. Each subgroup
// gathers one edge's E-row slice per iter -> 8 independent 128B gathers in flight
// per wave; lane covers 8 dims via one 16B load. Metadata prefetched one step ahead.
__global__ __launch_bounds__(256) void spmm_bf16(const float2* __restrict__ packed,
                                                 const int* __restrict__ row_ptr,
                                                 const unsigned short* __restrict__ Ebf,
                                                 float* __restrict__ Lm) {
    int wid = (blockIdx.x * blockDim.x + threadIdx.x) >> 6;
    int lane = threadIdx.x & 63;
    if (wid >= N_CNT) return;
    int s = row_ptr[wid];
    int e = row_ptr[wid + 1];
    int sub = lane >> 3;   // edge slot within group of 8
    int sl = lane & 7;     // covers dims 8*sl .. 8*sl+7
    float a0 = 0.f, a1 = 0.f, a2 = 0.f, a3 = 0.f;
    float a4 = 0.f, a5 = 0.f, a6 = 0.f, a7 = 0.f;
    int i = s + sub;
    float2 rec = (i < e) ? packed[i] : make_float2(0.f, __int_as_float(0));
    while (i < e) {
        int inext = i + 8;
        float2 rnext = (inext < e) ? packed[inext] : make_float2(0.f, __int_as_float(0));
        int c = __float_as_int(rec.y);
        uint4 ev = *(const uint4*)(Ebf + (size_t)c * D + 8 * sl);
        float v = rec.x;
        a0 += v * bf16_lo(ev.x); a1 += v * bf16_hi(ev.x);
        a2 += v * bf16_lo(ev.y); a3 += v * bf16_hi(ev.y);
        a4 += v * bf16_lo(ev.z); a5 += v * bf16_hi(ev.z);
        a6 += v * bf16_lo(ev.w); a7 += v * bf16_hi(ev.w);
        rec = rnext;
        i = inext;
    }
#pragma unroll
    for (int off = 32; off >= 8; off >>= 1) {
        a0 += __shfl_xor(a0, off, 64); a1 += __shfl_xor(a1, off, 64);
        a2 += __shfl_xor(a2, off, 64); a3 += __shfl_xor(a3, off, 64);
        a4 += __shfl_xor(a4, off, 64); a5 += __shfl_xor(a5, off, 64);
        a6 += __shfl_xor(a6, off, 64); a7 += __shfl_xor(a7, off, 64);
    }
    if (sub == 0) {
        float* dst = Lm + (size_t)wid * D + 8 * sl;
        *(float4*)dst = make_float4(a0, a1, a2, a3);
        *(float4*)(dst + 4) = make_float4(a4, a5, a6, a7);
    }
}

// ---------------- fused layer via MFMA: Y = leaky([Lm+E | Lm*E] @ [W1;W2] + b1+b2)
// un-normalized Y -> Ebf (bf16), row-normalized Y -> all_e[:, (layer+1)*64:...]
#define AP 136  // A/B^T row stride in shorts (128 + 8 pad -> 4-bank stagger)
__global__ __launch_bounds__(256) void layer_fused_mfma(const float* __restrict__ Lm,
                                                        unsigned short* __restrict__ Ebf,
                                                        const float* __restrict__ W1,
                                                        const float* __restrict__ b1,
                                                        const float* __restrict__ W2,
                                                        const float* __restrict__ b2,
                                                        float* __restrict__ all_e, int layer) {
    __shared__ unsigned short sBt[64 * AP];    // B^T[n][k] bf16 (k<64: W1, k>=64: W2)
    __shared__ float sBias[64];
    __shared__ unsigned short sA[4][16 * AP];  // per-wave A staging

    int t = threadIdx.x;
    for (int i = t; i < 4096; i += 256) {
        int k = i >> 6, n = i & 63;
        sBt[n * AP + k] = f32_to_bf16(W1[i]);
        sBt[n * AP + 64 + k] = f32_to_bf16(W2[i]);
    }
    if (t < 64) sBias[t] = b1[t] + b2[t];
    __syncthreads();

    int w = t >> 6, lane = t & 63;
    int quad = lane >> 4, l16 = lane & 15;

    short8 bfrag[4][4];
#pragma unroll
    for (int ks = 0; ks < 4; ks++)
#pragma unroll
        for (int ct = 0; ct < 4; ct++)
            bfrag[ks][ct] = *(const short8*)&sBt[(ct * 16 + l16) * AP + ks * 32 + quad * 8];

    float bias[4];
#pragma unroll
    for (int ct = 0; ct < 4; ct++) bias[ct] = sBias[ct * 16 + l16];

    unsigned short* A = sA[w];
    int col_off = (layer + 1) * 64;
    int nwaves = gridDim.x * 4;

    for (int tile = blockIdx.x * 4 + w; tile < N_CNT / 16; tile += nwaves) {
        int rbase = tile * 16;
#pragma unroll
        for (int p = 0; p < 4; p++) {
            int r = p * 4 + quad;
            int c = l16 * 4;
            float4 lv = *(const float4*)(Lm + (size_t)(rbase + r) * 64 + c);
            ushort4 eh = *(const ushort4*)(Ebf + (size_t)(rbase + r) * 64 + c);
            float e0 = bf16_to_f32(eh.x), e1 = bf16_to_f32(eh.y);
            float e2 = bf16_to_f32(eh.z), e3 = bf16_to_f32(eh.w);
            unsigned int x1a = f32_to_bf16(lv.x + e0) | ((unsigned int)f32_to_bf16(lv.y + e1) << 16);
            unsigned int x1b = f32_to_bf16(lv.z + e2) | ((unsigned int)f32_to_bf16(lv.w + e3) << 16);
            unsigned int x2a = f32_to_bf16(lv.x * e0) | ((unsigned int)f32_to_bf16(lv.y * e1) << 16);
            unsigned int x2b = f32_to_bf16(lv.z * e2) | ((unsigned int)f32_to_bf16(lv.w * e3) << 16);
            *(uint2*)&A[r * AP + c] = make_uint2(x1a, x1b);
            *(uint2*)&A[r * AP + 64 + c] = make_uint2(x2a, x2b);
        }
        floatx4 acc[4];
#pragma unroll
        for (int ct = 0; ct < 4; ct++) {
            acc[ct][0] = bias[ct]; acc[ct][1] = bias[ct];
            acc[ct][2] = bias[ct]; acc[ct][3] = bias[ct];
        }
#pragma unroll
        for (int ks = 0; ks < 4; ks++) {
            short8 af = *(const short8*)&A[l16 * AP + ks * 32 + quad * 8];
#pragma unroll
            for (int ct = 0; ct < 4; ct++)
                acc[ct] = __builtin_amdgcn_mfma_f32_16x16x32_bf16(af, bfrag[ks][ct], acc[ct], 0, 0, 0);
        }
        float y[4][4];
        float ssq[4] = {0.f, 0.f, 0.f, 0.f};
#pragma unroll
        for (int ct = 0; ct < 4; ct++)
#pragma unroll
            for (int reg = 0; reg < 4; reg++) {
                float v = acc[ct][reg];
                v = (v > 0.f) ? v : 0.2f * v;
                y[ct][reg] = v;
                ssq[reg] += v * v;
            }
#pragma unroll
        for (int reg = 0; reg < 4; reg++) {
            float ss = ssq[reg];
            ss += __shfl_xor(ss, 1, 64);
            ss += __shfl_xor(ss, 2, 64);
            ss += __shfl_xor(ss, 4, 64);
            ss += __shfl_xor(ss, 8, 64);
            ssq[reg] = fmaxf(sqrtf(ss), EPS_F);
        }
#pragma unroll
        for (int reg = 0; reg < 4; reg++) {
            int row = rbase + quad * 4 + reg;
            float inv = 1.0f / ssq[reg];
#pragma unroll
            for (int ct = 0; ct < 4; ct++) {
                int col = ct * 16 + l16;
                float v = y[ct][reg];
                Ebf[(size_t)row * 64 + col] = f32_to_bf16(v);
                all_e[(size_t)row * 256 + col_off + col] = v * inv;
            }
        }
    }
}

// ---------------- scoring: one wave per sample, per-sample partials (NO atomics)
__device__ __forceinline__ float dot4(float4 a, float4 b) {
    return a.x * b.x + a.y * b.y + a.z * b.z + a.w * b.w;
}

__global__ __launch_bounds__(256) void score_kernel(const float* __restrict__ all_e,
                                                    const int* __restrict__ users,
                                                    const int* __restrict__ pos,
                                                    const int* __restrict__ neg,
                                                    float4* __restrict__ partials) {
    int wid = (blockIdx.x * blockDim.x + threadIdx.x) >> 6;
    int lane = threadIdx.x & 63;
    if (wid >= BATCH) return;
    int ui = users[wid];
    int pi = pos[wid];
    int ni = neg[wid];
    const float4* uv4 = (const float4*)(all_e + (size_t)ui * 256);
    const float4* pv4 = (const float4*)(all_e + (size_t)pi * 256);
    const float4* nv4 = (const float4*)(all_e + (size_t)ni * 256);
    float4 uv = uv4[lane];
    float4 pv = pv4[lane];
    float4 nv = nv4[lane];
    float s_up = dot4(uv, pv);
    float s_un = dot4(uv, nv);
    float s_uu = dot4(uv, uv);
    float s_pp = dot4(pv, pv);
    float s_nn = dot4(nv, nv);
#pragma unroll
    for (int off = 32; off >= 1; off >>= 1) {
        s_up += __shfl_xor(s_up, off, 64);
        s_un += __shfl_xor(s_un, off, 64);
        s_uu += __shfl_xor(s_uu, off, 64);
        s_pp += __shfl_xor(s_pp, off, 64);
        s_nn += __shfl_xor(s_nn, off, 64);
    }
    if (lane == 0) {
        float x = s_up - s_un;
        float ls = fminf(x, 0.f) - log1pf(expf(-fabsf(x)));  // log_sigmoid
        partials[wid] = make_float4(-ls, s_uu, s_pp, s_nn);
    }
}

// single-block tree reduction over 4096 float4 partials + final scalar
__global__ __launch_bounds__(256) void reduce_finalize(const float4* __restrict__ partials,
                                                       float* __restrict__ out) {
    __shared__ float4 s[256];
    int t = threadIdx.x;
    float4 a = make_float4(0.f, 0.f, 0.f, 0.f);
    for (int i = t; i < BATCH; i += 256) {
        float4 p = partials[i];
        a.x += p.x; a.y += p.y; a.z += p.z; a.w += p.w;
    }
    s[t] = a;
    __syncthreads();
    for (int off = 128; off >= 1; off >>= 1) {
        if (t < off) {
            s[t].x += s[t + off].x;
            s[t].y += s[t + off].y;
            s[t].z += s[t + off].z;
            s[t].w += s[t + off].w;
        }
        __syncthreads();
    }
    if (t == 0) {
        float bpr = s[0].x / (float)BATCH;
        float l2norm = (s[0].y + s[0].z + sqrtf(s[0].w)) * 0.5f;
        out[0] = bpr + L2_REG_F * l2norm / (float)BATCH;
    }
}

extern "C" void kernel_launch(void* const* d_in, const int* in_sizes, int n_in,
                              void* d_out, int out_size, void* d_ws, size_t ws_size,
                              hipStream_t stream) {
    const int* users = (const int*)d_in[0];
    const int* pos_items = (const int*)d_in[1];
    const int* neg_items = (const int*)d_in[2];
    const int* rows = (const int*)d_in[3];
    const int* cols = (const int*)d_in[4];
    const float* vals = (const float*)d_in[5];
    const float* user_embed = (const float*)d_in[6];
    const float* item_embed = (const float*)d_in[7];
    const float* W1 = (const float*)d_in[8];
    const float* b1 = (const float*)d_in[9];
    const float* W2 = (const float*)d_in[10];
    const float* b2 = (const float*)d_in[11];
    float* out = (float*)d_out;

    char* ws = (char*)d_ws;
    size_t off_alle = 0;                                     // 102,400,000
    size_t off_Lm = off_alle + (size_t)N_CNT * 256 * 4;      // 25,600,000
    size_t off_packed = off_Lm + (size_t)N_CNT * D * 4;      // 25,600,000
    size_t off_Ebf = off_packed + (size_t)NNZ_CNT * 8;       // 12,800,000
    size_t off_rowptr = off_Ebf + (size_t)N_CNT * D * 2;     // 400,128
    size_t off_blkB = off_rowptr + 400128;                   // 2,048 (392 block sums)
    size_t off_bcnt = off_blkB + 2048;                       // 400,384 (391*256 ints)
    size_t off_part = off_bcnt + 400384;                     // 65,536

    float* all_e = (float*)(ws + off_alle);
    float2* bbuf = (float2*)(ws + off_alle);   // aliases all_e; dead before init_E runs
    float* Lm = (float*)(ws + off_Lm);
    float2* packed = (float2*)(ws + off_packed);
    unsigned short* Ebf = (unsigned short*)(ws + off_Ebf);
    int* row_ptr = (int*)(ws + off_rowptr);
    int* blkB = (int*)(ws + off_blkB);
    int* bcnt = (int*)(ws + off_bcnt);
    float4* partials = (float4*)(ws + off_part);

    // bucketed multisplit with exclusive per-(bucket,block) regions
    bucket_hist<<<SC_NBLK, 1024, 0, stream>>>(rows, bcnt);
    scan_p1<<<BCNT_NBLK, 256, 0, stream>>>(bcnt, blkB, BCNT_N);
    scan_p2<<<1, 512, 0, stream>>>(blkB, BCNT_NBLK);
    scan_p3<<<BCNT_NBLK, 256, 0, stream>>>(bcnt, blkB, bcnt, BCNT_N);  // in-place
    block_scatter<<<SC_NBLK, 1024, 0, stream>>>(rows, cols, vals, bcnt, bbuf);
    csr_finalize<<<NBUCKET, 1024, 0, stream>>>(bbuf, bcnt, row_ptr, packed);

    // embeddings (after csr_finalize: bbuf aliases all_e)
    init_E<<<(N_CNT * D) / 256, 256, 0, stream>>>(user_embed, item_embed, Ebf, all_e);

    for (int l = 0; l < LAYERS; l++) {
        spmm_bf16<<<(N_CNT * 64) / 256, 256, 0, stream>>>(packed, row_ptr, Ebf, Lm);
        layer_fused_mfma<<<784, 256, 0, stream>>>(Lm, Ebf, W1 + (size_t)l * 4096,
                                                  b1 + (size_t)l * 64, W2 + (size_t)l * 4096,
                                                  b2 + (size_t)l * 64, all_e, l);
    }

    score_kernel<<<(BATCH * 64) / 256, 256, 0, stream>>>(all_e, users, pos_items, neg_items,
                                                         partials);
    reduce_finalize<<<1, 256, 0, stream>>>(partials, out);
}

// Round 11
// 437.214 us; speedup vs baseline: 3.0589x; 1.0111x over previous
//
#include <hip/hip_runtime.h>
#include <hip/hip_bf16.h>
#include <math.h>

#define U_CNT 50000
#define I_CNT 50000
#define N_CNT 100000
#define D 64
#define NNZ_CNT 3200000
#define LAYERS 3
#define BATCH 4096
#define L2_REG_F 1e-5f
#define EPS_F 1e-12f

#define NBUCKET 391     // 256 rows per bucket
#define SC_NBLK 256     // scatter blocks (1 per CU), 1024 threads each
#define SC_CHUNK 12500  // NNZ / SC_NBLK
#define BCNT_N (NBUCKET * SC_NBLK)       // 100,096
#define BCNT_NBLK ((BCNT_N + 255) / 256) // 392

typedef __attribute__((ext_vector_type(8))) short short8;
typedef __attribute__((ext_vector_type(4))) float floatx4;

__device__ __forceinline__ unsigned short f32_to_bf16(float f) {
    unsigned int u = __float_as_uint(f);
    u += 0x7FFFu + ((u >> 16) & 1u);   // round-to-nearest-even
    return (unsigned short)(u >> 16);
}
__device__ __forceinline__ float bf16_to_f32(unsigned short h) {
    return __uint_as_float(((unsigned int)h) << 16);
}
__device__ __forceinline__ float bf16_lo(unsigned int u) {
    return __uint_as_float(u << 16);
}
__device__ __forceinline__ float bf16_hi(unsigned int u) {
    return __uint_as_float(u & 0xFFFF0000u);
}
__device__ __forceinline__ unsigned int pack_bf16(float a, float b) {
    return (unsigned int)f32_to_bf16(a) | ((unsigned int)f32_to_bf16(b) << 16);
}

// ---------------- init: all_e[:,0:64] = concat(ue,ie) fp32; E_bf = bf16 copy
__global__ void init_E(const float* __restrict__ ue, const float* __restrict__ ie,
                       unsigned short* __restrict__ Ebf, float* __restrict__ all_e) {
    int tid = blockIdx.x * blockDim.x + threadIdx.x;
    if (tid >= N_CNT * D) return;
    int row = tid >> 6;
    int d = tid & 63;
    float v = (row < U_CNT) ? ue[tid] : ie[tid - U_CNT * D];
    Ebf[tid] = f32_to_bf16(v);
    all_e[(size_t)row * 256 + d] = v;
}

// ---------------- generic hierarchical exclusive scan (n <= 512*256)
__global__ void scan_p1(const int* __restrict__ in, int* __restrict__ bsums, int n) {
    __shared__ int s[256];
    int t = threadIdx.x;
    int i = blockIdx.x * 256 + t;
    int v = (i < n) ? in[i] : 0;
    s[t] = v;
    __syncthreads();
    for (int off = 128; off >= 1; off >>= 1) {
        if (t < off) s[t] += s[t + off];
        __syncthreads();
    }
    if (t == 0) bsums[blockIdx.x] = s[0];
}

__global__ void scan_p2(int* __restrict__ bsums, int nblk) {
    __shared__ int s[512];
    int t = threadIdx.x;
    int v = (t < nblk) ? bsums[t] : 0;
    s[t] = v;
    __syncthreads();
    for (int off = 1; off < 512; off <<= 1) {
        int x = (t >= off) ? s[t - off] : 0;
        __syncthreads();
        s[t] += x;
        __syncthreads();
    }
    if (t < nblk) bsums[t] = s[t] - v;  // exclusive
}

__global__ void scan_p3(const int* __restrict__ in, const int* __restrict__ bsums,
                        int* __restrict__ out, int n) {
    __shared__ int s[256];
    int t = threadIdx.x;
    int i = blockIdx.x * 256 + t;
    int v = (i < n) ? in[i] : 0;
    s[t] = v;
    __syncthreads();
    for (int off = 1; off < 256; off <<= 1) {
        int x = (t >= off) ? s[t - off] : 0;
        __syncthreads();
        s[t] += x;
        __syncthreads();
    }
    if (i < n) out[i] = s[t] - v + bsums[blockIdx.x];
}

// ---------------- per-block bucket histogram -> bcnt[bucket*SC_NBLK + blk]
__global__ __launch_bounds__(1024) void bucket_hist(const int* __restrict__ rows,
                                                    int* __restrict__ bcnt) {
    __shared__ int h[NBUCKET];
    int blk = blockIdx.x, t = threadIdx.x;
    if (t < NBUCKET) h[t] = 0;
    __syncthreads();
    int s = blk * SC_CHUNK, e = s + SC_CHUNK;
    for (int i = s + t; i < e; i += 1024) atomicAdd(&h[rows[i] >> 8], 1);
    __syncthreads();
    if (t < NBUCKET) bcnt[t * SC_NBLK + blk] = h[t];
}

// ---------------- scatter into per-(bucket,block) EXCLUSIVE regions (LDS cursors)
__global__ __launch_bounds__(1024) void block_scatter(const int* __restrict__ rows,
                                                      const int* __restrict__ cols,
                                                      const float* __restrict__ vals,
                                                      const int* __restrict__ boff,
                                                      float2* __restrict__ bbuf) {
    __shared__ int cur[NBUCKET];
    int blk = blockIdx.x, t = threadIdx.x;
    if (t < NBUCKET) cur[t] = boff[t * SC_NBLK + blk];
    __syncthreads();
    int s = blk * SC_CHUNK, e = s + SC_CHUNK;
    for (int i = s + t; i < e; i += 1024) {
        int r = rows[i];
        int b = r >> 8;
        int p = atomicAdd(&cur[b], 1);
        unsigned int bits = ((unsigned int)(r & 255) << 17) | (unsigned int)cols[i];
        bbuf[p] = make_float2(vals[i], __uint_as_float(bits));
    }
}

// ---------------- per-bucket: LDS rowlocal hist -> LDS scan -> row_ptr -> row-sorted packed
__global__ __launch_bounds__(1024) void csr_finalize(const float2* __restrict__ bbuf,
                                                     const int* __restrict__ boff,
                                                     int* __restrict__ row_ptr,
                                                     float2* __restrict__ packed) {
    __shared__ int h[256];
    __shared__ int cur[256];
    int b = blockIdx.x, t = threadIdx.x;
    int s = boff[b * SC_NBLK];
    int e = (b == NBUCKET - 1) ? NNZ_CNT : boff[(b + 1) * SC_NBLK];
    if (t < 256) h[t] = 0;
    __syncthreads();
    for (int i = s + t; i < e; i += 1024)
        atomicAdd(&h[__float_as_uint(bbuf[i].y) >> 17], 1);
    __syncthreads();
    int v = (t < 256) ? h[t] : 0;
    for (int off = 1; off < 256; off <<= 1) {   // Hillis-Steele inclusive scan (t<256)
        int x = (t >= off && t < 256) ? h[t - off] : 0;
        __syncthreads();
        if (t < 256) h[t] += x;
        __syncthreads();
    }
    if (t < 256) {
        int start = s + h[t] - v;  // exclusive + bucket base
        int row = (b << 8) + t;
        if (row < N_CNT) row_ptr[row] = start;
        cur[t] = start;
        if (b == 0 && t == 0) row_ptr[N_CNT] = NNZ_CNT;
    }
    __syncthreads();
    for (int i = s + t; i < e; i += 1024) {
        float2 rec = bbuf[i];
        unsigned int bits = __float_as_uint(rec.y);
        int p = atomicAdd(&cur[bits >> 17], 1);
        packed[p] = make_float2(rec.x, __int_as_float(bits & 0x1FFFFu));
    }
}

// ---------------- SpMM: one wave per row; 16 subgroups x 4 lanes.
// Subgroup = (edge slot [0,8), row half {0,1}); lane loads 16B of a 64B half-row
// -> 16 independent gathers in flight per wave. bf16 Lm output.
__global__ __launch_bounds__(256) void spmm_bf16(const float2* __restrict__ packed,
                                                 const int* __restrict__ row_ptr,
                                                 const unsigned short* __restrict__ Ebf,
                                                 unsigned short* __restrict__ Lm) {
    int wid = (blockIdx.x * blockDim.x + threadIdx.x) >> 6;
    int lane = threadIdx.x & 63;
    if (wid >= N_CNT) return;
    int s = row_ptr[wid];
    int e = row_ptr[wid + 1];
    int sub = lane >> 2;       // [0,16)
    int sl = lane & 3;         // [0,4)
    int eidx = sub >> 1;       // edge slot [0,8)
    int half = sub & 1;        // row half
    int dbase = half * 32 + sl * 8;  // this lane's 8 dims
    float a0 = 0.f, a1 = 0.f, a2 = 0.f, a3 = 0.f;
    float a4 = 0.f, a5 = 0.f, a6 = 0.f, a7 = 0.f;
    int i = s + eidx;
    float2 rec = (i < e) ? packed[i] : make_float2(0.f, __int_as_float(0));
    while (i < e) {
        int inext = i + 8;
        float2 rnext = (inext < e) ? packed[inext] : make_float2(0.f, __int_as_float(0));
        int c = __float_as_int(rec.y);
        uint4 ev = *(const uint4*)(Ebf + (size_t)c * D + dbase);
        float v = rec.x;
        a0 += v * bf16_lo(ev.x); a1 += v * bf16_hi(ev.x);
        a2 += v * bf16_lo(ev.y); a3 += v * bf16_hi(ev.y);
        a4 += v * bf16_lo(ev.z); a5 += v * bf16_hi(ev.z);
        a6 += v * bf16_lo(ev.w); a7 += v * bf16_hi(ev.w);
        rec = rnext;
        i = inext;
    }
    // combine the 8 edge slots: lanes with same (half,sl) differ by 8/16/32 in lane id
#pragma unroll
    for (int off = 32; off >= 8; off >>= 1) {
        a0 += __shfl_xor(a0, off, 64); a1 += __shfl_xor(a1, off, 64);
        a2 += __shfl_xor(a2, off, 64); a3 += __shfl_xor(a3, off, 64);
        a4 += __shfl_xor(a4, off, 64); a5 += __shfl_xor(a5, off, 64);
        a6 += __shfl_xor(a6, off, 64); a7 += __shfl_xor(a7, off, 64);
    }
    if (eidx == 0) {  // lanes 0..7 (sub 0 and 1) write 16B each -> 128B row
        unsigned int* dst = (unsigned int*)(Lm + (size_t)wid * D + dbase);
        *(uint4*)dst = make_uint4(pack_bf16(a0, a1), pack_bf16(a2, a3),
                                  pack_bf16(a4, a5), pack_bf16(a6, a7));
    }
}

// ---------------- fused layer via MFMA: Y = leaky([Lm+E | Lm*E] @ [W1;W2] + b1+b2)
// un-normalized Y -> Ebf (bf16), row-normalized Y -> all_e[:, (layer+1)*64:...]
#define AP 136  // A/B^T row stride in shorts (128 + 8 pad -> 4-bank stagger)
__global__ __launch_bounds__(256) void layer_fused_mfma(const unsigned short* __restrict__ Lm,
                                                        unsigned short* __restrict__ Ebf,
                                                        const float* __restrict__ W1,
                                                        const float* __restrict__ b1,
                                                        const float* __restrict__ W2,
                                                        const float* __restrict__ b2,
                                                        float* __restrict__ all_e, int layer) {
    __shared__ unsigned short sBt[64 * AP];    // B^T[n][k] bf16 (k<64: W1, k>=64: W2)
    __shared__ float sBias[64];
    __shared__ unsigned short sA[4][16 * AP];  // per-wave A staging

    int t = threadIdx.x;
    for (int i = t; i < 4096; i += 256) {
        int k = i >> 6, n = i & 63;
        sBt[n * AP + k] = f32_to_bf16(W1[i]);
        sBt[n * AP + 64 + k] = f32_to_bf16(W2[i]);
    }
    if (t < 64) sBias[t] = b1[t] + b2[t];
    __syncthreads();

    int w = t >> 6, lane = t & 63;
    int quad = lane >> 4, l16 = lane & 15;

    short8 bfrag[4][4];
#pragma unroll
    for (int ks = 0; ks < 4; ks++)
#pragma unroll
        for (int ct = 0; ct < 4; ct++)
            bfrag[ks][ct] = *(const short8*)&sBt[(ct * 16 + l16) * AP + ks * 32 + quad * 8];

    float bias[4];
#pragma unroll
    for (int ct = 0; ct < 4; ct++) bias[ct] = sBias[ct * 16 + l16];

    unsigned short* A = sA[w];
    int col_off = (layer + 1) * 64;
    int nwaves = gridDim.x * 4;

    for (int tile = blockIdx.x * 4 + w; tile < N_CNT / 16; tile += nwaves) {
        int rbase = tile * 16;
#pragma unroll
        for (int p = 0; p < 4; p++) {
            int r = p * 4 + quad;
            int c = l16 * 4;
            uint2 lw = *(const uint2*)(Lm + (size_t)(rbase + r) * 64 + c);
            float l0 = bf16_lo(lw.x), l1 = bf16_hi(lw.x);
            float l2 = bf16_lo(lw.y), l3 = bf16_hi(lw.y);
            ushort4 eh = *(const ushort4*)(Ebf + (size_t)(rbase + r) * 64 + c);
            float e0 = bf16_to_f32(eh.x), e1 = bf16_to_f32(eh.y);
            float e2 = bf16_to_f32(eh.z), e3 = bf16_to_f32(eh.w);
            *(uint2*)&A[r * AP + c] = make_uint2(pack_bf16(l0 + e0, l1 + e1),
                                                pack_bf16(l2 + e2, l3 + e3));
            *(uint2*)&A[r * AP + 64 + c] = make_uint2(pack_bf16(l0 * e0, l1 * e1),
                                                      pack_bf16(l2 * e2, l3 * e3));
        }
        floatx4 acc[4];
#pragma unroll
        for (int ct = 0; ct < 4; ct++) {
            acc[ct][0] = bias[ct]; acc[ct][1] = bias[ct];
            acc[ct][2] = bias[ct]; acc[ct][3] = bias[ct];
        }
#pragma unroll
        for (int ks = 0; ks < 4; ks++) {
            short8 af = *(const short8*)&A[l16 * AP + ks * 32 + quad * 8];
#pragma unroll
            for (int ct = 0; ct < 4; ct++)
                acc[ct] = __builtin_amdgcn_mfma_f32_16x16x32_bf16(af, bfrag[ks][ct], acc[ct], 0, 0, 0);
        }
        float y[4][4];
        float ssq[4] = {0.f, 0.f, 0.f, 0.f};
#pragma unroll
        for (int ct = 0; ct < 4; ct++)
#pragma unroll
            for (int reg = 0; reg < 4; reg++) {
                float v = acc[ct][reg];
                v = (v > 0.f) ? v : 0.2f * v;
                y[ct][reg] = v;
                ssq[reg] += v * v;
            }
#pragma unroll
        for (int reg = 0; reg < 4; reg++) {
            float ss = ssq[reg];
            ss += __shfl_xor(ss, 1, 64);
            ss += __shfl_xor(ss, 2, 64);
            ss += __shfl_xor(ss, 4, 64);
            ss += __shfl_xor(ss, 8, 64);
            ssq[reg] = fmaxf(sqrtf(ss), EPS_F);
        }
#pragma unroll
        for (int reg = 0; reg < 4; reg++) {
            int row = rbase + quad * 4 + reg;
            float inv = 1.0f / ssq[reg];
#pragma unroll
            for (int ct = 0; ct < 4; ct++) {
                int col = ct * 16 + l16;
                float v = y[ct][reg];
                Ebf[(size_t)row * 64 + col] = f32_to_bf16(v);
                all_e[(size_t)row * 256 + col_off + col] = v * inv;
            }
        }
    }
}

// ---------------- scoring: one wave per sample, per-sample partials (NO atomics)
__device__ __forceinline__ float dot4(float4 a, float4 b) {
    return a.x * b.x + a.y * b.y + a.z * b.z + a.w * b.w;
}

__global__ __launch_bounds__(256) void score_kernel(const float* __restrict__ all_e,
                                                    const int* __restrict__ users,
                                                    const int* __restrict__ pos,
                                                    const int* __restrict__ neg,
                                                    float4* __restrict__ partials) {
    int wid = (blockIdx.x * blockDim.x + threadIdx.x) >> 6;
    int lane = threadIdx.x & 63;
    if (wid >= BATCH) return;
    int ui = users[wid];
    int pi = pos[wid];
    int ni = neg[wid];
    const float4* uv4 = (const float4*)(all_e + (size_t)ui * 256);
    const float4* pv4 = (const float4*)(all_e + (size_t)pi * 256);
    const float4* nv4 = (const float4*)(all_e + (size_t)ni * 256);
    float4 uv = uv4[lane];
    float4 pv = pv4[lane];
    float4 nv = nv4[lane];
    float s_up = dot4(uv, pv);
    float s_un = dot4(uv, nv);
    float s_uu = dot4(uv, uv);
    float s_pp = dot4(pv, pv);
    float s_nn = dot4(nv, nv);
#pragma unroll
    for (int off = 32; off >= 1; off >>= 1) {
        s_up += __shfl_xor(s_up, off, 64);
        s_un += __shfl_xor(s_un, off, 64);
        s_uu += __shfl_xor(s_uu, off, 64);
        s_pp += __shfl_xor(s_pp, off, 64);
        s_nn += __shfl_xor(s_nn, off, 64);
    }
    if (lane == 0) {
        float x = s_up - s_un;
        float ls = fminf(x, 0.f) - log1pf(expf(-fabsf(x)));  // log_sigmoid
        partials[wid] = make_float4(-ls, s_uu, s_pp, s_nn);
    }
}

// single-block tree reduction over 4096 float4 partials + final scalar
__global__ __launch_bounds__(256) void reduce_finalize(const float4* __restrict__ partials,
                                                       float* __restrict__ out) {
    __shared__ float4 s[256];
    int t = threadIdx.x;
    float4 a = make_float4(0.f, 0.f, 0.f, 0.f);
    for (int i = t; i < BATCH; i += 256) {
        float4 p = partials[i];
        a.x += p.x; a.y += p.y; a.z += p.z; a.w += p.w;
    }
    s[t] = a;
    __syncthreads();
    for (int off = 128; off >= 1; off >>= 1) {
        if (t < off) {
            s[t].x += s[t + off].x;
            s[t].y += s[t + off].y;
            s[t].z += s[t + off].z;
            s[t].w += s[t + off].w;
        }
        __syncthreads();
    }
    if (t == 0) {
        float bpr = s[0].x / (float)BATCH;
        float l2norm = (s[0].y + s[0].z + sqrtf(s[0].w)) * 0.5f;
        out[0] = bpr + L2_REG_F * l2norm / (float)BATCH;
    }
}

extern "C" void kernel_launch(void* const* d_in, const int* in_sizes, int n_in,
                              void* d_out, int out_size, void* d_ws, size_t ws_size,
                              hipStream_t stream) {
    const int* users = (const int*)d_in[0];
    const int* pos_items = (const int*)d_in[1];
    const int* neg_items = (const int*)d_in[2];
    const int* rows = (const int*)d_in[3];
    const int* cols = (const int*)d_in[4];
    const float* vals = (const float*)d_in[5];
    const float* user_embed = (const float*)d_in[6];
    const float* item_embed = (const float*)d_in[7];
    const float* W1 = (const float*)d_in[8];
    const float* b1 = (const float*)d_in[9];
    const float* W2 = (const float*)d_in[10];
    const float* b2 = (const float*)d_in[11];
    float* out = (float*)d_out;

    char* ws = (char*)d_ws;
    // workspace layout (round-7 structure, Lm stored bf16): total ~154.5 MB
    size_t off_alle = 0;                                     // 102,400,000
    size_t off_packed = off_alle + (size_t)N_CNT * 256 * 4;  // 25,600,000
    size_t off_Ebf = off_packed + (size_t)NNZ_CNT * 8;       // 12,800,000
    size_t off_Lm = off_Ebf + (size_t)N_CNT * D * 2;         // 12,800,000 (bf16)
    size_t off_rowptr = off_Lm + (size_t)N_CNT * D * 2;      // 400,128
    size_t off_blkB = off_rowptr + 400128;                   // 2,048
    size_t off_bcnt = off_blkB + 2048;                       // 400,384
    size_t off_part = off_bcnt + 400384;                     // 65,536

    float* all_e = (float*)(ws + off_alle);
    float2* bbuf = (float2*)(ws + off_alle);   // aliases all_e; dead before init_E runs
    float2* packed = (float2*)(ws + off_packed);
    unsigned short* Ebf = (unsigned short*)(ws + off_Ebf);
    unsigned short* Lm = (unsigned short*)(ws + off_Lm);
    int* row_ptr = (int*)(ws + off_rowptr);
    int* blkB = (int*)(ws + off_blkB);
    int* bcnt = (int*)(ws + off_bcnt);
    float4* partials = (float4*)(ws + off_part);

    // bucketed multisplit with exclusive per-(bucket,block) regions
    bucket_hist<<<SC_NBLK, 1024, 0, stream>>>(rows, bcnt);
    scan_p1<<<BCNT_NBLK, 256, 0, stream>>>(bcnt, blkB, BCNT_N);
    scan_p2<<<1, 512, 0, stream>>>(blkB, BCNT_NBLK);
    scan_p3<<<BCNT_NBLK, 256, 0, stream>>>(bcnt, blkB, bcnt, BCNT_N);  // in-place
    block_scatter<<<SC_NBLK, 1024, 0, stream>>>(rows, cols, vals, bcnt, bbuf);
    csr_finalize<<<NBUCKET, 1024, 0, stream>>>(bbuf, bcnt, row_ptr, packed);

    // embeddings (after csr_finalize: bbuf aliases all_e)
    init_E<<<(N_CNT * D) / 256, 256, 0, stream>>>(user_embed, item_embed, Ebf, all_e);

    for (int l = 0; l < LAYERS; l++) {
        spmm_bf16<<<(N_CNT * 64) / 256, 256, 0, stream>>>(packed, row_ptr, Ebf, Lm);
        layer_fused_mfma<<<784, 256, 0, stream>>>(Lm, Ebf, W1 + (size_t)l * 4096,
                                                  b1 + (size_t)l * 64, W2 + (size_t)l * 4096,
                                                  b2 + (size_t)l * 64, all_e, l);
    }

    score_kernel<<<(BATCH * 64) / 256, 256, 0, stream>>>(all_e, users, pos_items, neg_items,
                                                         partials);
    reduce_finalize<<<1, 256, 0, stream>>>(partials, out);
}